// Round 1
// 862.960 us; speedup vs baseline: 1.2904x; 1.2904x over previous
//
#include <hip/hip_runtime.h>
#include <hip/hip_bf16.h>
#include <hip/hip_fp16.h>
#include <stdint.h>

// MultiHeadSelfAttention: B=4 S=2048 D=2048 H=16 DH=128, fp32 in/out.
// out[q] = softmax_row(S)[k<=q] @ V  - 1e9 * suffixV[q]   (mask AFTER softmax)
// Error budget: threshold 4.1e9 absolute; output ~2e11 from the -1e9 term.
// Pipeline: wtrans -> (xcvt + gemm_qkv2) x3 (m97-style global_load_lds GEMM)
//           -> attn3 (causal flash, balanced+dbuf+swizzled) -> vscan
//           -> transadd -> out_gemm2.

#define Bdim 4
#define Sdim 2048
#define Ddim 2048
#define Hdim 16
#define DHdim 128

typedef __attribute__((ext_vector_type(4))) float f32x4;
typedef __attribute__((ext_vector_type(8))) short s16x8;
typedef unsigned short u16;

__device__ __forceinline__ u16 f2b(float f) {  // RNE
  union { float f; uint32_t u; } x; x.f = f;
  uint32_t r = x.u + 0x7FFFu + ((x.u >> 16) & 1u);
  return (u16)(r >> 16);
}
__device__ __forceinline__ u16 f2b_rtz(float f) {  // truncate (1 op)
  union { float f; uint32_t u; } x; x.f = f;
  return (u16)(x.u >> 16);
}
__device__ __forceinline__ float b2f(u16 b) {
  union { uint32_t u; float f; } x; x.u = ((uint32_t)b) << 16;
  return x.f;
}
// async global->LDS, 16B/lane; LDS dest = wave-uniform base + lane*16
__device__ __forceinline__ void gl_lds16(const u16* g, u16* l) {
  __builtin_amdgcn_global_load_lds(
      (const __attribute__((address_space(1))) void*)g,
      (__attribute__((address_space(3))) void*)l, 16, 0, 0);
}

// ---------------- 1) transpose + convert weights: WT[n][k] = bf16(W[k][n]) ----
__global__ __launch_bounds__(256) void wtrans_kernel(
    const float* __restrict__ Wq, const float* __restrict__ Wk,
    const float* __restrict__ Wv, const float* __restrict__ Wo,
    u16* __restrict__ WT) {
  __shared__ float tile[64][65];
  const int z = blockIdx.z;
  const float* W = (z == 0) ? Wq : (z == 1) ? Wk : (z == 2) ? Wv : Wo;
  u16* dst = WT + (size_t)z * (size_t)Ddim * Ddim;
  const int kb = blockIdx.x * 64;
  const int nb = blockIdx.y * 64;
  const int c = threadIdx.x & 63;
  const int r4 = threadIdx.x >> 6;
#pragma unroll
  for (int i = 0; i < 16; ++i) {
    int r = r4 * 16 + i;
    tile[r][c] = W[(size_t)(kb + r) * Ddim + nb + c];
  }
  __syncthreads();
#pragma unroll
  for (int i = 0; i < 16; ++i) {
    int r = r4 * 16 + i;
    dst[(size_t)(nb + r) * Ddim + kb + c] = f2b(tile[c][r]);
  }
}

// ---------------- 2a) fp32 -> bf16 (RTZ via v_perm, memory-bound) -----------
__global__ __launch_bounds__(256) void xcvt_kernel(const float* __restrict__ X,
                                                   u16* __restrict__ Xb) {
  const size_t i = ((size_t)blockIdx.x * 256 + threadIdx.x) * 8;
  const uint4 a = *(const uint4*)(X + i);
  const uint4 b = *(const uint4*)(X + i + 4);
  uint4 o;
  o.x = __builtin_amdgcn_perm(a.y, a.x, 0x07060302u);
  o.y = __builtin_amdgcn_perm(a.w, a.z, 0x07060302u);
  o.z = __builtin_amdgcn_perm(b.y, b.x, 0x07060302u);
  o.w = __builtin_amdgcn_perm(b.w, b.z, 0x07060302u);
  *(uint4*)(Xb + i) = o;
}

// ---------------- 2b) m97-style GEMM: C[128x128] = A[128xK] * B^T[128xK] ----
__global__ __launch_bounds__(256) void gemm_qkv2_kernel(
    const u16* __restrict__ Xb, const u16* __restrict__ Wt,
    const float* __restrict__ bias, u16* __restrict__ Out, int z) {
  __shared__ u16 As[128 * 32];
  __shared__ u16 Bs[128 * 32];
  const int t = threadIdx.x;
  const int lane = t & 63;
  const int w = t >> 6;
  const int wm = w & 1, wn = w >> 1;
  const int l15 = lane & 15, quad = lane >> 4;
  const int m0 = blockIdx.x * 128;
  const int n0 = blockIdx.y * 128;
  const f32x4 zero4 = {0.f, 0.f, 0.f, 0.f};
  f32x4 acc[4][4];
#pragma unroll
  for (int i = 0; i < 4; ++i)
#pragma unroll
    for (int j = 0; j < 4; ++j) acc[i][j] = zero4;
  const int srow = w * 16 + (lane >> 2);  // staging row in 64-row group
  const int scol = (lane & 3) * 8;        // u16 col
  const u16* ga = Xb + (size_t)(m0 + srow) * Ddim + scol;
  const u16* gb = Wt + (size_t)(n0 + srow) * Ddim + scol;
  u16* la = &As[(w * 16) * 32];  // wave-uniform LDS base
  u16* lb = &Bs[(w * 16) * 32];
  for (int kb = 0; kb < Ddim / 32; ++kb) {
    gl_lds16(ga, la);
    gl_lds16(ga + (size_t)64 * Ddim, la + 64 * 32);
    gl_lds16(gb, lb);
    gl_lds16(gb + (size_t)64 * Ddim, lb + 64 * 32);
    ga += 32;
    gb += 32;
    __syncthreads();
    s16x8 af[4], bf[4];
#pragma unroll
    for (int mt = 0; mt < 4; ++mt)
      af[mt] = *(const s16x8*)(&As[(wm * 64 + mt * 16 + l15) * 32 + quad * 8]);
#pragma unroll
    for (int nt = 0; nt < 4; ++nt)
      bf[nt] = *(const s16x8*)(&Bs[(wn * 64 + nt * 16 + l15) * 32 + quad * 8]);
#pragma unroll
    for (int mt = 0; mt < 4; ++mt)
#pragma unroll
      for (int nt = 0; nt < 4; ++nt)
        acc[mt][nt] = __builtin_amdgcn_mfma_f32_16x16x32_bf16(
            af[mt], bf[nt], acc[mt][nt], 0, 0, 0);
    __syncthreads();
  }
#pragma unroll
  for (int nt = 0; nt < 4; ++nt) {
    const int gn = n0 + wn * 64 + nt * 16 + l15;
    const float bia = bias[gn];
    const int h = gn >> 7, dh = gn & 127;
#pragma unroll
    for (int mt = 0; mt < 4; ++mt) {
#pragma unroll
      for (int r = 0; r < 4; ++r) {
        const int gm = m0 + wm * 64 + mt * 16 + quad * 4 + r;
        const int b = gm >> 11, s = gm & 2047;
        const u16 val = f2b(acc[mt][nt][r] + bia);
        if (z < 2)
          Out[((size_t)(b * Hdim + h) * Sdim + s) * DHdim + dh] = val;
        else
          Out[((size_t)(b * Hdim + h) * DHdim + dh) * Sdim + s] = val;
      }
    }
  }
}

// ---------------- 3) attention (causal flash, balanced + dbuf + swizzled) ---
// Each block handles q-tile pair {15-bx, bx} -> uniform 34 k-tile steps.
// K/V double-buffered in LDS via global_load_lds with pre-swizzled global
// source (rule #21: linear dest + inverse-swz source + swz on read).
// Swizzle: byte ^= (row&7)<<4 on Ks[64][128], Vs[128][64], Ps[32][64].
#define SCALE2 0.12751744f  // log2(e)/sqrt(128)
__global__ __launch_bounds__(256, 2) void attn3_kernel(
    const u16* __restrict__ Qb, const u16* __restrict__ Kb,
    const u16* __restrict__ Vt, u16* __restrict__ Ao) {
  __shared__ u16 Ks[2][64 * 128];   // 2 x 16 KB
  __shared__ u16 Vs[2][128 * 64];   // 2 x 16 KB
  __shared__ u16 Ps[4][32 * 64];    // 16 KB, per-wave
  const int t = threadIdx.x;
  const int lane = t & 63;
  const int w = t >> 6;
  const int l15 = lane & 15, quad = lane >> 4;
  // XCD-aware swizzle (bijective: 512 = 8*64): XCD n gets bh 8n..8n+7.
  const int bid0 = (int)blockIdx.x + ((int)blockIdx.y << 3);
  const int nbid = (bid0 & 7) * 64 + (bid0 >> 3);
  const int bx = nbid & 7;
  const int bh = nbid >> 3;
  const u16* Kbase = Kb + (size_t)bh * Sdim * DHdim;
  const u16* Vbase = Vt + (size_t)bh * DHdim * Sdim;
  u16* Pw = &Ps[w][0];
  const f32x4 zero4 = {0.f, 0.f, 0.f, 0.f};

  // staging geometry: per wave 4 gl_lds of 1 KB each for K and V
  const int klr = lane >> 4;         // K: row within 4-row group
  const int kcs = (lane & 15) << 4;  // K: byte col (pre-swizzle)
  const int vlr = lane >> 3;         // V: row within 8-row group
  const int vcs = (lane & 7) << 4;   // V: byte col

  auto stage = [&](int kt_, int buf_) {
#pragma unroll
    for (int p = 0; p < 4; ++p) {
      const int r = (w << 4) + (p << 2) + klr;
      gl_lds16(Kbase + (((size_t)kt_ * 64 + r) << 7) +
                   ((kcs ^ ((r & 7) << 4)) >> 1),
               &Ks[buf_][(w << 11) + (p << 9)]);
    }
#pragma unroll
    for (int p = 0; p < 4; ++p) {
      const int r = (w << 5) + (p << 3) + vlr;
      gl_lds16(Vbase + (size_t)r * Sdim + kt_ * 64 +
                   ((vcs ^ ((r & 7) << 4)) >> 1),
               &Vs[buf_][(w << 11) + (p << 9)]);
    }
  };

  for (int half = 0; half < 2; ++half) {
    const int qt = half ? bx : 15 - bx;
    const int qw0 = qt * 128 + w * 32;
    const int ktd = qw0 >> 6;
    const bool lowhalf = (qw0 & 63) == 0;
    const int ntiles = qt * 2 + 2;
    const u16* Qp = Qb + ((size_t)bh * Sdim + qw0) * DHdim;
    s16x8 qf[2][4];
#pragma unroll
    for (int mt = 0; mt < 2; ++mt)
#pragma unroll
      for (int ks = 0; ks < 4; ++ks)
        qf[mt][ks] = *(const s16x8*)(Qp + (size_t)(mt * 16 + l15) * DHdim +
                                     ks * 32 + quad * 8);
    f32x4 o1[2][8];
#pragma unroll
    for (int i = 0; i < 2; ++i)
#pragma unroll
      for (int j = 0; j < 8; ++j) o1[i][j] = zero4;
    float lp[2][4];
#pragma unroll
    for (int i = 0; i < 2; ++i)
#pragma unroll
      for (int j = 0; j < 4; ++j) lp[i][j] = 0.f;

    __syncthreads();   // prior readers of LDS done (half=1)
    stage(0, 0);
    __syncthreads();   // vmcnt(0) drain: tile 0 resident
    int cur = 0;
    for (int kt = 0; kt < ntiles; ++kt) {
      if (kt + 1 < ntiles) stage(kt + 1, cur ^ 1);  // async, hidden by compute
      if (kt <= ktd) {
        // ---- QK^T ----
        f32x4 sc[2][4];
#pragma unroll
        for (int i = 0; i < 2; ++i)
#pragma unroll
          for (int j = 0; j < 4; ++j) sc[i][j] = zero4;
#pragma unroll
        for (int ks = 0; ks < 4; ++ks) {
          s16x8 kf[4];
#pragma unroll
          for (int nt = 0; nt < 4; ++nt) {
            const int R = nt * 16 + l15;
            kf[nt] = *(const s16x8*)((const char*)&Ks[cur][0] + (R << 8) +
                                     ((ks * 64 + (quad << 4)) ^
                                      ((R & 7) << 4)));
          }
          __builtin_amdgcn_s_setprio(1);
#pragma unroll
          for (int mt = 0; mt < 2; ++mt)
#pragma unroll
            for (int nt = 0; nt < 4; ++nt)
              sc[mt][nt] = __builtin_amdgcn_mfma_f32_16x16x32_bf16(
                  qf[mt][ks], kf[nt], sc[mt][nt], 0, 0, 0);
          __builtin_amdgcn_s_setprio(0);
        }
        // ---- exp + row-sum partials ----
#pragma unroll
        for (int mt = 0; mt < 2; ++mt)
#pragma unroll
          for (int r = 0; r < 4; ++r) {
            float p0 = exp2f(sc[mt][0][r] * SCALE2);
            float p1 = exp2f(sc[mt][1][r] * SCALE2);
            float p2 = exp2f(sc[mt][2][r] * SCALE2);
            float p3 = exp2f(sc[mt][3][r] * SCALE2);
            sc[mt][0][r] = p0; sc[mt][1][r] = p1;
            sc[mt][2][r] = p2; sc[mt][3][r] = p3;
            lp[mt][r] += (p0 + p1) + (p2 + p3);
          }
        // ---- P store (swizzled) ----
        const bool diag = (kt == ktd);
        if (!diag) {
#pragma unroll
          for (int mt = 0; mt < 2; ++mt)
#pragma unroll
            for (int nt = 0; nt < 4; ++nt)
#pragma unroll
              for (int r = 0; r < 4; ++r) {
                const int row = mt * 16 + quad * 4 + r;
                *(u16*)((char*)Pw + (row << 7) +
                        ((((nt * 16 + l15) << 1)) ^ ((row & 7) << 4))) =
                    f2b_rtz(sc[mt][nt][r]);
              }
        } else {
          const int ntlo = lowhalf ? 0 : 2;
#pragma unroll
          for (int mt = 0; mt < 2; ++mt)
#pragma unroll
            for (int nt = 0; nt < 4; ++nt) {
              if (!lowhalf && nt < 2) {
#pragma unroll
                for (int r = 0; r < 4; ++r) {
                  const int row = mt * 16 + quad * 4 + r;
                  *(u16*)((char*)Pw + (row << 7) +
                          ((((nt * 16 + l15) << 1)) ^ ((row & 7) << 4))) =
                      f2b_rtz(sc[mt][nt][r]);
                }
              } else if (nt >= ntlo && nt < ntlo + 2) {
                const int kg = kt * 64 + nt * 16 + l15;
#pragma unroll
                for (int r = 0; r < 4; ++r) {
                  const int qg = qw0 + mt * 16 + quad * 4 + r;
                  const int row = mt * 16 + quad * 4 + r;
                  *(u16*)((char*)Pw + (row << 7) +
                          ((((nt * 16 + l15) << 1)) ^ ((row & 7) << 4))) =
                      (kg > qg) ? (u16)0 : f2b_rtz(sc[mt][nt][r]);
                }
              }
            }
        }
        // ---- PV ----
        const int k2max = (diag && lowhalf) ? 1 : 2;
#pragma unroll
        for (int k2 = 0; k2 < 2; ++k2) {
          if (k2 >= k2max) break;
          s16x8 pf[2];
#pragma unroll
          for (int mt = 0; mt < 2; ++mt) {
            const int R = mt * 16 + l15;
            pf[mt] = *(const s16x8*)((const char*)Pw + (R << 7) +
                                     ((k2 * 64 + (quad << 4)) ^
                                      ((R & 7) << 4)));
          }
          __builtin_amdgcn_s_setprio(1);
#pragma unroll
          for (int nt = 0; nt < 8; ++nt) {
            const int R = nt * 16 + l15;
            const s16x8 vf = *(const s16x8*)(
                (const char*)&Vs[cur][0] + (R << 7) +
                ((k2 * 64 + (quad << 4)) ^ ((R & 7) << 4)));
#pragma unroll
            for (int mt = 0; mt < 2; ++mt)
              o1[mt][nt] = __builtin_amdgcn_mfma_f32_16x16x32_bf16(
                  pf[mt], vf, o1[mt][nt], 0, 0, 0);
          }
          __builtin_amdgcn_s_setprio(0);
        }
      }
      __syncthreads();  // readers of buf done + next tile's stage arrived
      cur ^= 1;
    }
    // ---- epilogue ----
    const int b = bh >> 4, h = bh & 15;
#pragma unroll
    for (int mt = 0; mt < 2; ++mt) {
#pragma unroll
      for (int r = 0; r < 4; ++r) {
        float l = lp[mt][r];
        l += __shfl_xor(l, 1);
        l += __shfl_xor(l, 2);
        l += __shfl_xor(l, 4);
        l += __shfl_xor(l, 8);
        const float invl = 1.0f / l;
        const int sq = qw0 + mt * 16 + quad * 4 + r;
        const size_t rowb = ((size_t)b * Sdim + sq) * Ddim + h * DHdim;
#pragma unroll
        for (int nt = 0; nt < 8; ++nt)
          Ao[rowb + nt * 16 + l15] = f2b(o1[mt][nt][r] * invl);
      }
    }
  }
}

// ---------------- 4) suffix scan of V: Vsuf[bh][dh][q] = fp16(sum_{k>q} V) --
__global__ __launch_bounds__(256) void vscan_kernel(const u16* __restrict__ Vt,
                                                    u16* __restrict__ Vsuf) {
  const int t = threadIdx.x, lane = t & 63, w = t >> 6;
  const int idx = blockIdx.x * 4 + w;  // bh*128 + dh
  const u16* src = Vt + (size_t)idx * Sdim;
  u16* dst = Vsuf + (size_t)idx * Sdim;
  const int c0 = lane * 32;
  float v[32];
#pragma unroll
  for (int p = 0; p < 4; ++p) {
    uint4 raw = *(const uint4*)(src + c0 + p * 8);
    const u16* rp = (const u16*)&raw;
#pragma unroll
    for (int j = 0; j < 8; ++j) v[p * 8 + j] = b2f(rp[j]);
  }
  float tot = 0.f;
#pragma unroll
  for (int j = 0; j < 32; ++j) tot += v[j];
  float T = tot;
#pragma unroll
  for (int off = 1; off < 64; off <<= 1) {
    float u = __shfl_down(T, off);
    if (lane + off < 64) T += u;
  }
  float s = T - tot;
  u16 outv[32];
#pragma unroll
  for (int j = 31; j >= 0; --j) {
    outv[j] = __half_as_ushort(__float2half(s));
    s += v[j];
  }
#pragma unroll
  for (int p = 0; p < 4; ++p)
    *(uint4*)(dst + c0 + p * 8) = *(uint4*)(outv + p * 8);
}

// ---------------- 5) Ao[b][q][h,dh] -= 1e9 * Vsuf[bh][dh][q] (transpose) ----
__global__ __launch_bounds__(256) void transadd_kernel(
    const u16* __restrict__ Vsuf, u16* __restrict__ Ao) {
  __shared__ float tile[64][65];
  const int qt = blockIdx.x;
  const int dt = blockIdx.y;
  const int bh = blockIdx.z;
  const int t = threadIdx.x;
  const int r = t >> 2, c0 = (t & 3) * 16;
  const u16* sp =
      Vsuf + ((size_t)bh * 128 + dt * 64 + r) * Sdim + qt * 64 + c0;
#pragma unroll
  for (int h2 = 0; h2 < 2; ++h2) {
    uint4 raw = *(const uint4*)(sp + h2 * 8);
    const u16* rp = (const u16*)&raw;
#pragma unroll
    for (int j = 0; j < 8; ++j)
      tile[c0 + h2 * 8 + j][r] = __half2float(__ushort_as_half(rp[j]));
  }
  __syncthreads();
  const int b = bh >> 4, h = bh & 15;
  u16* ap =
      Ao + ((size_t)b * Sdim + qt * 64 + r) * Ddim + h * 128 + dt * 64 + c0;
#pragma unroll
  for (int h2 = 0; h2 < 2; ++h2) {
    uint4 raw = *(uint4*)(ap + h2 * 8);
    u16* rp = (u16*)&raw;
#pragma unroll
    for (int j = 0; j < 8; ++j) {
      float a = b2f(rp[j]) - 1e9f * tile[r][c0 + h2 * 8 + j];
      rp[j] = f2b(a);
    }
    *(uint4*)(ap + h2 * 8) = raw;
  }
}

// ---------------- 6) output projection GEMM (m97-style) ---------------------
__global__ __launch_bounds__(256) void out_gemm2_kernel(
    const u16* __restrict__ Ao, const u16* __restrict__ WoT,
    const float* __restrict__ bo, float* __restrict__ out) {
  __shared__ u16 As[128 * 32];
  __shared__ u16 Bs[128 * 32];
  const int t = threadIdx.x;
  const int lane = t & 63;
  const int w = t >> 6;
  const int wm = w & 1, wn = w >> 1;
  const int l15 = lane & 15, quad = lane >> 4;
  const int m0 = blockIdx.x * 128;
  const int n0 = blockIdx.y * 128;
  const f32x4 zero4 = {0.f, 0.f, 0.f, 0.f};
  f32x4 acc[4][4];
#pragma unroll
  for (int i = 0; i < 4; ++i)
#pragma unroll
    for (int j = 0; j < 4; ++j) acc[i][j] = zero4;
  const int srow = w * 16 + (lane >> 2);
  const int scol = (lane & 3) * 8;
  const u16* ga = Ao + (size_t)(m0 + srow) * Ddim + scol;
  const u16* gb = WoT + (size_t)(n0 + srow) * Ddim + scol;
  u16* la = &As[(w * 16) * 32];
  u16* lb = &Bs[(w * 16) * 32];
  for (int kb = 0; kb < Ddim / 32; ++kb) {
    gl_lds16(ga, la);
    gl_lds16(ga + (size_t)64 * Ddim, la + 64 * 32);
    gl_lds16(gb, lb);
    gl_lds16(gb + (size_t)64 * Ddim, lb + 64 * 32);
    ga += 32;
    gb += 32;
    __syncthreads();
    s16x8 af[4], bf[4];
#pragma unroll
    for (int mt = 0; mt < 4; ++mt)
      af[mt] = *(const s16x8*)(&As[(wm * 64 + mt * 16 + l15) * 32 + quad * 8]);
#pragma unroll
    for (int nt = 0; nt < 4; ++nt)
      bf[nt] = *(const s16x8*)(&Bs[(wn * 64 + nt * 16 + l15) * 32 + quad * 8]);
#pragma unroll
    for (int mt = 0; mt < 4; ++mt)
#pragma unroll
      for (int nt = 0; nt < 4; ++nt)
        acc[mt][nt] = __builtin_amdgcn_mfma_f32_16x16x32_bf16(
            af[mt], bf[nt], acc[mt][nt], 0, 0, 0);
    __syncthreads();
  }
#pragma unroll
  for (int nt = 0; nt < 4; ++nt) {
    const int gn = n0 + wn * 64 + nt * 16 + l15;
    const float bia = bo[gn];
#pragma unroll
    for (int mt = 0; mt < 4; ++mt)
#pragma unroll
      for (int r = 0; r < 4; ++r) {
        const int gm = m0 + wm * 64 + mt * 16 + quad * 4 + r;
        out[(size_t)gm * Ddim + gn] = acc[mt][nt][r] + bia;
      }
  }
}

// ---------------- launcher ---------------------------------------------------
extern "C" void kernel_launch(void* const* d_in, const int* in_sizes, int n_in,
                              void* d_out, int out_size, void* d_ws,
                              size_t ws_size, hipStream_t stream) {
  (void)in_sizes; (void)n_in; (void)out_size; (void)ws_size;
  const float* q = (const float*)d_in[0];
  const float* k = (const float*)d_in[1];
  const float* v = (const float*)d_in[2];
  const float* Wq = (const float*)d_in[3];
  const float* bq = (const float*)d_in[4];
  const float* Wk = (const float*)d_in[5];
  const float* bk = (const float*)d_in[6];
  const float* Wv = (const float*)d_in[7];
  const float* bv = (const float*)d_in[8];
  const float* Wo = (const float*)d_in[9];
  const float* bo = (const float*)d_in[10];
  float* out = (float*)d_out;
  char* ws = (char*)d_ws;
  // ws: WT 33.5M | Qb 33.5M (Vsuf later) | Kb | Vt | Xb 33.5M (Ao later)
  u16* WT = (u16*)(ws);
  u16* Qb = (u16*)(ws + 33554432);
  u16* Kb = (u16*)(ws + 67108864);
  u16* Vt = (u16*)(ws + 100663296);
  u16* Xb = (u16*)(ws + 134217728);  // scratch for bf16 inputs (pre-attn)
  u16* Ao = Xb;                       // Xb dead after gemms
  u16* WoT = WT + (size_t)3 * Ddim * Ddim;
  u16* Vsuf = Qb;                     // Qb dead after attn3

  wtrans_kernel<<<dim3(32, 32, 4), dim3(256), 0, stream>>>(Wq, Wk, Wv, Wo, WT);
  const float* Xs[3] = {q, k, v};
  const float* bs[3] = {bq, bk, bv};
  u16* Os[3] = {Qb, Kb, Vt};
  for (int z = 0; z < 3; ++z) {
    xcvt_kernel<<<dim3(8192), dim3(256), 0, stream>>>(Xs[z], Xb);
    gemm_qkv2_kernel<<<dim3(64, 16), dim3(256), 0, stream>>>(
        Xb, WT + (size_t)z * Ddim * Ddim, bs[z], Os[z], z);
  }
  attn3_kernel<<<dim3(8, 64), dim3(256), 0, stream>>>(Qb, Kb, Vt, Ao);
  vscan_kernel<<<dim3(2048), dim3(256), 0, stream>>>(Vt, Vsuf);
  transadd_kernel<<<dim3(32, 2, 64), dim3(256), 0, stream>>>(Vsuf, Ao);
  out_gemm2_kernel<<<dim3(64, 16), dim3(256), 0, stream>>>(Ao, WoT, bo, out);
}

// Round 3
// 810.384 us; speedup vs baseline: 1.3741x; 1.0649x over previous
//
#include <hip/hip_runtime.h>
#include <hip/hip_bf16.h>
#include <hip/hip_fp16.h>
#include <stdint.h>

// MultiHeadSelfAttention: B=4 S=2048 D=2048 H=16 DH=128, fp32 in/out.
// out[q] = softmax_row(S)[k<=q] @ V  - 1e9 * suffixV[q]   (mask AFTER softmax)
// Error budget: threshold 4.1e9 absolute; output ~2e11 from the -1e9 term.
// Pipeline: wtrans -> (xcvt + gemm256<0/2>) x3 -> attn3 (causal flash)
//           -> vscan -> transadd -> gemm256<3>.
// gemm256: 256x256 tile, BK=32, 8 waves, 4-deep LDS ring, counted vmcnt(8),
//          raw s_barrier (no drain), XOR-swizzled LDS rows (T2+T3+T4+T5).
//          sched_barrier(0) after every asm waitcnt (rule #18 hardening).

#define Bdim 4
#define Sdim 2048
#define Ddim 2048
#define Hdim 16
#define DHdim 128

typedef __attribute__((ext_vector_type(4))) float f32x4;
typedef __attribute__((ext_vector_type(8))) short s16x8;
typedef __attribute__((ext_vector_type(4))) unsigned short u16x4;
typedef unsigned short u16;

__device__ __forceinline__ u16 f2b(float f) {  // RNE
  union { float f; uint32_t u; } x; x.f = f;
  uint32_t r = x.u + 0x7FFFu + ((x.u >> 16) & 1u);
  return (u16)(r >> 16);
}
__device__ __forceinline__ u16 f2b_rtz(float f) {  // truncate (1 op)
  union { float f; uint32_t u; } x; x.f = f;
  return (u16)(x.u >> 16);
}
__device__ __forceinline__ float b2f(u16 b) {
  union { uint32_t u; float f; } x; x.u = ((uint32_t)b) << 16;
  return x.f;
}
// async global->LDS, 16B/lane; LDS dest = wave-uniform base + lane*16
__device__ __forceinline__ void gl_lds16(const u16* g, u16* l) {
  __builtin_amdgcn_global_load_lds(
      (const __attribute__((address_space(1))) void*)g,
      (__attribute__((address_space(3))) void*)l, 16, 0, 0);
}

// ---------------- 1) transpose + convert weights: WT[n][k] = bf16(W[k][n]) ----
__global__ __launch_bounds__(256) void wtrans_kernel(
    const float* __restrict__ Wq, const float* __restrict__ Wk,
    const float* __restrict__ Wv, const float* __restrict__ Wo,
    u16* __restrict__ WT) {
  __shared__ float tile[64][65];
  const int z = blockIdx.z;
  const float* W = (z == 0) ? Wq : (z == 1) ? Wk : (z == 2) ? Wv : Wo;
  u16* dst = WT + (size_t)z * (size_t)Ddim * Ddim;
  const int kb = blockIdx.x * 64;
  const int nb = blockIdx.y * 64;
  const int c = threadIdx.x & 63;
  const int r4 = threadIdx.x >> 6;
#pragma unroll
  for (int i = 0; i < 16; ++i) {
    int r = r4 * 16 + i;
    tile[r][c] = W[(size_t)(kb + r) * Ddim + nb + c];
  }
  __syncthreads();
#pragma unroll
  for (int i = 0; i < 16; ++i) {
    int r = r4 * 16 + i;
    dst[(size_t)(nb + r) * Ddim + kb + c] = f2b(tile[c][r]);
  }
}

// ---------------- 2a) fp32 -> bf16 (RTZ via v_perm, memory-bound) -----------
__global__ __launch_bounds__(256) void xcvt_kernel(const float* __restrict__ X,
                                                   u16* __restrict__ Xb) {
  const size_t i = ((size_t)blockIdx.x * 256 + threadIdx.x) * 8;
  const uint4 a = *(const uint4*)(X + i);
  const uint4 b = *(const uint4*)(X + i + 4);
  uint4 o;
  o.x = __builtin_amdgcn_perm(a.y, a.x, 0x07060302u);
  o.y = __builtin_amdgcn_perm(a.w, a.z, 0x07060302u);
  o.z = __builtin_amdgcn_perm(b.y, b.x, 0x07060302u);
  o.w = __builtin_amdgcn_perm(b.w, b.z, 0x07060302u);
  *(uint4*)(Xb + i) = o;
}

// ---------------- 2b) 256x256 GEMM: C = A[8192xK] * B^T, K=2048 -------------
// Z=0: head-split u16 out [B,H,S,DH]; Z=2: transposed u16 [B,H,DH,S] (8B
// packed stores); Z=3: fp32 out [M,N].
// 8 waves (2m x 4n), per-wave 128x64 out. LDS ring of 4 K-tiles (BK=32),
// 128 KB. Swizzle: 16B-slot ^= ((row>>1)&3)<<4 (involution; pre-swizzled
// global_load_lds source + swizzled ds_read, rule #21).
template <int Z>
__global__ __launch_bounds__(512, 2) void gemm256_kernel(
    const u16* __restrict__ A, const u16* __restrict__ Bm,
    const float* __restrict__ bias, void* __restrict__ OutV) {
  __shared__ u16 Asl[4][256 * 32];
  __shared__ u16 Bsl[4][256 * 32];
  const int t = threadIdx.x;
  const int lane = t & 63;
  const int w = t >> 6;            // 0..7
  const int wm = w >> 2, wn = w & 3;
  const int l15 = lane & 15, quad = lane >> 4;
  const int n0 = blockIdx.x * 256;  // bid%8 == n-tile -> per-XCD B-panel reuse
  const int m0 = blockIdx.y * 256;

  // staging geometry: wave w stages rows [w*32, w*32+32) of A and B tiles.
  const int srow = w * 32 + (lane >> 2);
  const int scb = ((((lane & 3) << 4) ^ (((srow >> 1) & 3) << 4)) >> 1);
  const u16* gA = A + (size_t)(m0 + srow) * Ddim + scb;
  const u16* gB = Bm + (size_t)(n0 + srow) * Ddim + scb;
  u16* lA0 = &Asl[0][0] + (w * 32) * 32;  // wave-uniform LDS base
  u16* lB0 = &Bsl[0][0] + (w * 32) * 32;

  // fragment byte offsets (fixed per lane; add buffer base per iteration)
  int aoff[8], boff[4];
#pragma unroll
  for (int mt = 0; mt < 8; ++mt) {
    const int r = wm * 128 + mt * 16 + l15;
    aoff[mt] = r * 64 + ((quad << 4) ^ (((r >> 1) & 3) << 4));
  }
#pragma unroll
  for (int nt = 0; nt < 4; ++nt) {
    const int r = wn * 64 + nt * 16 + l15;
    boff[nt] = r * 64 + ((quad << 4) ^ (((r >> 1) & 3) << 4));
  }
  const f32x4 zero4 = {0.f, 0.f, 0.f, 0.f};
  f32x4 acc[8][4];
#pragma unroll
  for (int i = 0; i < 8; ++i)
#pragma unroll
    for (int j = 0; j < 4; ++j) acc[i][j] = zero4;

  auto stage = [&](int kt_, int buf_) {
    const u16* pa = gA + kt_ * 32;
    const u16* pb = gB + kt_ * 32;
    u16* da = lA0 + buf_ * (256 * 32);
    u16* db = lB0 + buf_ * (256 * 32);
    gl_lds16(pa, da);
    gl_lds16(pa + (size_t)16 * Ddim, da + 16 * 32);
    gl_lds16(pb, db);
    gl_lds16(pb + (size_t)16 * Ddim, db + 16 * 32);
  };
  auto compute = [&](int buf_) {
    const char* ab = (const char*)&Asl[buf_][0];
    const char* bb = (const char*)&Bsl[buf_][0];
    s16x8 af[8], bf[4];
#pragma unroll
    for (int mt = 0; mt < 8; ++mt) af[mt] = *(const s16x8*)(ab + aoff[mt]);
#pragma unroll
    for (int nt = 0; nt < 4; ++nt) bf[nt] = *(const s16x8*)(bb + boff[nt]);
    __builtin_amdgcn_s_setprio(1);
#pragma unroll
    for (int mt = 0; mt < 8; ++mt)
#pragma unroll
      for (int nt = 0; nt < 4; ++nt)
        acc[mt][nt] = __builtin_amdgcn_mfma_f32_16x16x32_bf16(
            af[mt], bf[nt], acc[mt][nt], 0, 0, 0);
    __builtin_amdgcn_s_setprio(0);
  };

  const int NK = Ddim / 32;  // 64
  // prologue: tiles 0,1,2 in flight; certify tile 0.
  stage(0, 0);
  stage(1, 1);
  stage(2, 2);
  __builtin_amdgcn_sched_barrier(0);
  asm volatile("s_waitcnt vmcnt(8)" ::: "memory");
  __builtin_amdgcn_sched_barrier(0);
  __builtin_amdgcn_s_barrier();
  int kt = 0;
  for (; kt < NK - 3; ++kt) {
    stage(kt + 3, (kt + 3) & 3);  // issue-early: ~2 iterations of cover
    compute(kt & 3);
    __builtin_amdgcn_sched_barrier(0);
    asm volatile("s_waitcnt vmcnt(8)" ::: "memory");  // tile kt+1 landed
    __builtin_amdgcn_sched_barrier(0);
    __builtin_amdgcn_s_barrier();
  }
  compute(kt & 3);  // kt = NK-3
  __builtin_amdgcn_sched_barrier(0);
  asm volatile("s_waitcnt vmcnt(4)" ::: "memory");
  __builtin_amdgcn_sched_barrier(0);
  __builtin_amdgcn_s_barrier();
  ++kt;
  compute(kt & 3);  // kt = NK-2
  __builtin_amdgcn_sched_barrier(0);
  asm volatile("s_waitcnt vmcnt(0)" ::: "memory");
  __builtin_amdgcn_sched_barrier(0);
  __builtin_amdgcn_s_barrier();
  ++kt;
  compute(kt & 3);  // kt = NK-1

  // ---- epilogue ----
  if (Z <= 1) {
    u16* Out = (u16*)OutV;
#pragma unroll
    for (int nt = 0; nt < 4; ++nt) {
      const int gn = n0 + wn * 64 + nt * 16 + l15;
      const float bia = bias[gn];
      const int h = gn >> 7, dh = gn & 127;
#pragma unroll
      for (int mt = 0; mt < 8; ++mt) {
#pragma unroll
        for (int r = 0; r < 4; ++r) {
          const int gm = m0 + wm * 128 + mt * 16 + quad * 4 + r;
          const int b = gm >> 11, s = gm & 2047;
          Out[((size_t)(b * Hdim + h) * Sdim + s) * DHdim + dh] =
              f2b(acc[mt][nt][r] + bia);
        }
      }
    }
  } else if (Z == 2) {
    u16* Out = (u16*)OutV;
#pragma unroll
    for (int nt = 0; nt < 4; ++nt) {
      const int gn = n0 + wn * 64 + nt * 16 + l15;
      const float bia = bias[gn];
      const int h = gn >> 7, dh = gn & 127;
#pragma unroll
      for (int mt = 0; mt < 8; ++mt) {
        const int gm = m0 + wm * 128 + mt * 16 + quad * 4;
        const int b = gm >> 11, s = gm & 2047;
        u16x4 pk;
#pragma unroll
        for (int r = 0; r < 4; ++r) pk[r] = f2b(acc[mt][nt][r] + bia);
        *(u16x4*)(Out + ((size_t)(b * Hdim + h) * DHdim + dh) * Sdim + s) = pk;
      }
    }
  } else {
    float* Out = (float*)OutV;
#pragma unroll
    for (int nt = 0; nt < 4; ++nt) {
      const int gn = n0 + wn * 64 + nt * 16 + l15;
      const float bia = bias[gn];
#pragma unroll
      for (int mt = 0; mt < 8; ++mt) {
#pragma unroll
        for (int r = 0; r < 4; ++r) {
          const int gm = m0 + wm * 128 + mt * 16 + quad * 4 + r;
          Out[(size_t)gm * Ddim + gn] = acc[mt][nt][r] + bia;
        }
      }
    }
  }
}

// ---------------- 3) attention (causal flash, balanced + dbuf + swizzled) ---
#define SCALE2 0.12751744f  // log2(e)/sqrt(128)
__global__ __launch_bounds__(256, 2) void attn3_kernel(
    const u16* __restrict__ Qb, const u16* __restrict__ Kb,
    const u16* __restrict__ Vt, u16* __restrict__ Ao) {
  __shared__ u16 Ks[2][64 * 128];   // 2 x 16 KB
  __shared__ u16 Vs[2][128 * 64];   // 2 x 16 KB
  __shared__ u16 Ps[4][32 * 64];    // 16 KB, per-wave
  const int t = threadIdx.x;
  const int lane = t & 63;
  const int w = t >> 6;
  const int l15 = lane & 15, quad = lane >> 4;
  // XCD-aware swizzle (bijective: 512 = 8*64): XCD n gets bh 8n..8n+7.
  const int bid0 = (int)blockIdx.x + ((int)blockIdx.y << 3);
  const int nbid = (bid0 & 7) * 64 + (bid0 >> 3);
  const int bx = nbid & 7;
  const int bh = nbid >> 3;
  const u16* Kbase = Kb + (size_t)bh * Sdim * DHdim;
  const u16* Vbase = Vt + (size_t)bh * DHdim * Sdim;
  u16* Pw = &Ps[w][0];
  const f32x4 zero4 = {0.f, 0.f, 0.f, 0.f};

  const int klr = lane >> 4;
  const int kcs = (lane & 15) << 4;
  const int vlr = lane >> 3;
  const int vcs = (lane & 7) << 4;

  auto stage = [&](int kt_, int buf_) {
#pragma unroll
    for (int p = 0; p < 4; ++p) {
      const int r = (w << 4) + (p << 2) + klr;
      gl_lds16(Kbase + (((size_t)kt_ * 64 + r) << 7) +
                   ((kcs ^ ((r & 7) << 4)) >> 1),
               &Ks[buf_][(w << 11) + (p << 9)]);
    }
#pragma unroll
    for (int p = 0; p < 4; ++p) {
      const int r = (w << 5) + (p << 3) + vlr;
      gl_lds16(Vbase + (size_t)r * Sdim + kt_ * 64 +
                   ((vcs ^ ((r & 7) << 4)) >> 1),
               &Vs[buf_][(w << 11) + (p << 9)]);
    }
  };

  for (int half = 0; half < 2; ++half) {
    const int qt = half ? bx : 15 - bx;
    const int qw0 = qt * 128 + w * 32;
    const int ktd = qw0 >> 6;
    const bool lowhalf = (qw0 & 63) == 0;
    const int ntiles = qt * 2 + 2;
    const u16* Qp = Qb + ((size_t)bh * Sdim + qw0) * DHdim;
    s16x8 qf[2][4];
#pragma unroll
    for (int mt = 0; mt < 2; ++mt)
#pragma unroll
      for (int ks = 0; ks < 4; ++ks)
        qf[mt][ks] = *(const s16x8*)(Qp + (size_t)(mt * 16 + l15) * DHdim +
                                     ks * 32 + quad * 8);
    f32x4 o1[2][8];
#pragma unroll
    for (int i = 0; i < 2; ++i)
#pragma unroll
      for (int j = 0; j < 8; ++j) o1[i][j] = zero4;
    float lp[2][4];
#pragma unroll
    for (int i = 0; i < 2; ++i)
#pragma unroll
      for (int j = 0; j < 4; ++j) lp[i][j] = 0.f;

    __syncthreads();   // prior readers of LDS done (half=1)
    stage(0, 0);
    __syncthreads();   // vmcnt(0) drain: tile 0 resident
    int cur = 0;
    for (int kt = 0; kt < ntiles; ++kt) {
      if (kt + 1 < ntiles) stage(kt + 1, cur ^ 1);  // async, hidden by compute
      if (kt <= ktd) {
        // ---- QK^T ----
        f32x4 sc[2][4];
#pragma unroll
        for (int i = 0; i < 2; ++i)
#pragma unroll
          for (int j = 0; j < 4; ++j) sc[i][j] = zero4;
#pragma unroll
        for (int ks = 0; ks < 4; ++ks) {
          s16x8 kf[4];
#pragma unroll
          for (int nt = 0; nt < 4; ++nt) {
            const int R = nt * 16 + l15;
            kf[nt] = *(const s16x8*)((const char*)&Ks[cur][0] + (R << 8) +
                                     ((ks * 64 + (quad << 4)) ^
                                      ((R & 7) << 4)));
          }
          __builtin_amdgcn_s_setprio(1);
#pragma unroll
          for (int mt = 0; mt < 2; ++mt)
#pragma unroll
            for (int nt = 0; nt < 4; ++nt)
              sc[mt][nt] = __builtin_amdgcn_mfma_f32_16x16x32_bf16(
                  qf[mt][ks], kf[nt], sc[mt][nt], 0, 0, 0);
          __builtin_amdgcn_s_setprio(0);
        }
        // ---- exp + row-sum partials ----
#pragma unroll
        for (int mt = 0; mt < 2; ++mt)
#pragma unroll
          for (int r = 0; r < 4; ++r) {
            float p0 = exp2f(sc[mt][0][r] * SCALE2);
            float p1 = exp2f(sc[mt][1][r] * SCALE2);
            float p2 = exp2f(sc[mt][2][r] * SCALE2);
            float p3 = exp2f(sc[mt][3][r] * SCALE2);
            sc[mt][0][r] = p0; sc[mt][1][r] = p1;
            sc[mt][2][r] = p2; sc[mt][3][r] = p3;
            lp[mt][r] += (p0 + p1) + (p2 + p3);
          }
        // ---- P store (swizzled) ----
        const bool diag = (kt == ktd);
        if (!diag) {
#pragma unroll
          for (int mt = 0; mt < 2; ++mt)
#pragma unroll
            for (int nt = 0; nt < 4; ++nt)
#pragma unroll
              for (int r = 0; r < 4; ++r) {
                const int row = mt * 16 + quad * 4 + r;
                *(u16*)((char*)Pw + (row << 7) +
                        ((((nt * 16 + l15) << 1)) ^ ((row & 7) << 4))) =
                    f2b_rtz(sc[mt][nt][r]);
              }
        } else {
          const int ntlo = lowhalf ? 0 : 2;
#pragma unroll
          for (int mt = 0; mt < 2; ++mt)
#pragma unroll
            for (int nt = 0; nt < 4; ++nt) {
              if (!lowhalf && nt < 2) {
#pragma unroll
                for (int r = 0; r < 4; ++r) {
                  const int row = mt * 16 + quad * 4 + r;
                  *(u16*)((char*)Pw + (row << 7) +
                          ((((nt * 16 + l15) << 1)) ^ ((row & 7) << 4))) =
                      f2b_rtz(sc[mt][nt][r]);
                }
              } else if (nt >= ntlo && nt < ntlo + 2) {
                const int kg = kt * 64 + nt * 16 + l15;
#pragma unroll
                for (int r = 0; r < 4; ++r) {
                  const int qg = qw0 + mt * 16 + quad * 4 + r;
                  const int row = mt * 16 + quad * 4 + r;
                  *(u16*)((char*)Pw + (row << 7) +
                          ((((nt * 16 + l15) << 1)) ^ ((row & 7) << 4))) =
                      (kg > qg) ? (u16)0 : f2b_rtz(sc[mt][nt][r]);
                }
              }
            }
        }
        // ---- PV ----
        const int k2max = (diag && lowhalf) ? 1 : 2;
#pragma unroll
        for (int k2 = 0; k2 < 2; ++k2) {
          if (k2 >= k2max) break;
          s16x8 pf[2];
#pragma unroll
          for (int mt = 0; mt < 2; ++mt) {
            const int R = mt * 16 + l15;
            pf[mt] = *(const s16x8*)((const char*)Pw + (R << 7) +
                                     ((k2 * 64 + (quad << 4)) ^
                                      ((R & 7) << 4)));
          }
          __builtin_amdgcn_s_setprio(1);
#pragma unroll
          for (int nt = 0; nt < 8; ++nt) {
            const int R = nt * 16 + l15;
            const s16x8 vf = *(const s16x8*)(
                (const char*)&Vs[cur][0] + (R << 7) +
                ((k2 * 64 + (quad << 4)) ^ ((R & 7) << 4)));
#pragma unroll
            for (int mt = 0; mt < 2; ++mt)
              o1[mt][nt] = __builtin_amdgcn_mfma_f32_16x16x32_bf16(
                  pf[mt], vf, o1[mt][nt], 0, 0, 0);
          }
          __builtin_amdgcn_s_setprio(0);
        }
      }
      __syncthreads();  // readers of buf done + next tile's stage arrived
      cur ^= 1;
    }
    // ---- epilogue ----
    const int b = bh >> 4, h = bh & 15;
#pragma unroll
    for (int mt = 0; mt < 2; ++mt) {
#pragma unroll
      for (int r = 0; r < 4; ++r) {
        float l = lp[mt][r];
        l += __shfl_xor(l, 1);
        l += __shfl_xor(l, 2);
        l += __shfl_xor(l, 4);
        l += __shfl_xor(l, 8);
        const float invl = 1.0f / l;
        const int sq = qw0 + mt * 16 + quad * 4 + r;
        const size_t rowb = ((size_t)b * Sdim + sq) * Ddim + h * DHdim;
#pragma unroll
        for (int nt = 0; nt < 8; ++nt)
          Ao[rowb + nt * 16 + l15] = f2b(o1[mt][nt][r] * invl);
      }
    }
  }
}

// ---------------- 4) suffix scan of V: Vsuf[bh][dh][q] = fp16(sum_{k>q} V) --
__global__ __launch_bounds__(256) void vscan_kernel(const u16* __restrict__ Vt,
                                                    u16* __restrict__ Vsuf) {
  const int t = threadIdx.x, lane = t & 63, w = t >> 6;
  const int idx = blockIdx.x * 4 + w;  // bh*128 + dh
  const u16* src = Vt + (size_t)idx * Sdim;
  u16* dst = Vsuf + (size_t)idx * Sdim;
  const int c0 = lane * 32;
  float v[32];
#pragma unroll
  for (int p = 0; p < 4; ++p) {
    uint4 raw = *(const uint4*)(src + c0 + p * 8);
    const u16* rp = (const u16*)&raw;
#pragma unroll
    for (int j = 0; j < 8; ++j) v[p * 8 + j] = b2f(rp[j]);
  }
  float tot = 0.f;
#pragma unroll
  for (int j = 0; j < 32; ++j) tot += v[j];
  float T = tot;
#pragma unroll
  for (int off = 1; off < 64; off <<= 1) {
    float u = __shfl_down(T, off);
    if (lane + off < 64) T += u;
  }
  float s = T - tot;
  u16 outv[32];
#pragma unroll
  for (int j = 31; j >= 0; --j) {
    outv[j] = __half_as_ushort(__float2half(s));
    s += v[j];
  }
#pragma unroll
  for (int p = 0; p < 4; ++p)
    *(uint4*)(dst + c0 + p * 8) = *(uint4*)(outv + p * 8);
}

// ---------------- 5) Ao[b][q][h,dh] -= 1e9 * Vsuf[bh][dh][q] (transpose) ----
__global__ __launch_bounds__(256) void transadd_kernel(
    const u16* __restrict__ Vsuf, u16* __restrict__ Ao) {
  __shared__ float tile[64][65];
  const int qt = blockIdx.x;
  const int dt = blockIdx.y;
  const int bh = blockIdx.z;
  const int t = threadIdx.x;
  const int r = t >> 2, c0 = (t & 3) * 16;
  const u16* sp =
      Vsuf + ((size_t)bh * 128 + dt * 64 + r) * Sdim + qt * 64 + c0;
#pragma unroll
  for (int h2 = 0; h2 < 2; ++h2) {
    uint4 raw = *(const uint4*)(sp + h2 * 8);
    const u16* rp = (const u16*)&raw;
#pragma unroll
    for (int j = 0; j < 8; ++j)
      tile[c0 + h2 * 8 + j][r] = __half2float(__ushort_as_half(rp[j]));
  }
  __syncthreads();
  const int b = bh >> 4, h = bh & 15;
  u16* ap =
      Ao + ((size_t)b * Sdim + qt * 64 + r) * Ddim + h * 128 + dt * 64 + c0;
#pragma unroll
  for (int h2 = 0; h2 < 2; ++h2) {
    uint4 raw = *(uint4*)(ap + h2 * 8);
    u16* rp = (u16*)&raw;
#pragma unroll
    for (int j = 0; j < 8; ++j) {
      float a = b2f(rp[j]) - 1e9f * tile[r][c0 + h2 * 8 + j];
      rp[j] = f2b(a);
    }
    *(uint4*)(ap + h2 * 8) = raw;
  }
}

// ---------------- launcher ---------------------------------------------------
extern "C" void kernel_launch(void* const* d_in, const int* in_sizes, int n_in,
                              void* d_out, int out_size, void* d_ws,
                              size_t ws_size, hipStream_t stream) {
  (void)in_sizes; (void)n_in; (void)out_size; (void)ws_size;
  const float* q = (const float*)d_in[0];
  const float* k = (const float*)d_in[1];
  const float* v = (const float*)d_in[2];
  const float* Wq = (const float*)d_in[3];
  const float* bq = (const float*)d_in[4];
  const float* Wk = (const float*)d_in[5];
  const float* bk = (const float*)d_in[6];
  const float* Wv = (const float*)d_in[7];
  const float* bv = (const float*)d_in[8];
  const float* Wo = (const float*)d_in[9];
  const float* bo = (const float*)d_in[10];
  float* out = (float*)d_out;
  char* ws = (char*)d_ws;
  // ws: WT 33.5M | Qb 33.5M (Vsuf later) | Kb | Vt | Xb 33.5M (Ao later)
  u16* WT = (u16*)(ws);
  u16* Qb = (u16*)(ws + 33554432);
  u16* Kb = (u16*)(ws + 67108864);
  u16* Vt = (u16*)(ws + 100663296);
  u16* Xb = (u16*)(ws + 134217728);  // scratch for bf16 inputs (pre-attn)
  u16* Ao = Xb;                       // Xb dead after gemms
  u16* WoT = WT + (size_t)3 * Ddim * Ddim;
  u16* Vsuf = Qb;                     // Qb dead after attn3

  wtrans_kernel<<<dim3(32, 32, 4), dim3(256), 0, stream>>>(Wq, Wk, Wv, Wo, WT);
  const float* Xs[3] = {q, k, v};
  const float* bs[3] = {bq, bk, bv};
  for (int z = 0; z < 3; ++z) {
    xcvt_kernel<<<dim3(8192), dim3(256), 0, stream>>>(Xs[z], Xb);
    if (z < 2)
      gemm256_kernel<0><<<dim3(8, 32), dim3(512), 0, stream>>>(
          Xb, WT + (size_t)z * Ddim * Ddim, bs[z], (z == 0) ? Qb : Kb);
    else
      gemm256_kernel<2><<<dim3(8, 32), dim3(512), 0, stream>>>(
          Xb, WT + (size_t)2 * Ddim * Ddim, bs[2], Vt);
  }
  attn3_kernel<<<dim3(8, 64), dim3(256), 0, stream>>>(Qb, Kb, Vt, Ao);
  vscan_kernel<<<dim3(2048), dim3(256), 0, stream>>>(Vt, Vsuf);
  transadd_kernel<<<dim3(32, 2, 64), dim3(256), 0, stream>>>(Vsuf, Ao);
  gemm256_kernel<3><<<dim3(8, 32), dim3(512), 0, stream>>>(Ao, WoT, bo, out);
}

// Round 4
// 751.181 us; speedup vs baseline: 1.4824x; 1.0788x over previous
//
#include <hip/hip_runtime.h>
#include <hip/hip_bf16.h>
#include <hip/hip_fp16.h>
#include <stdint.h>

// MultiHeadSelfAttention: B=4 S=2048 D=2048 H=16 DH=128, fp32 in/out.
// out[q] = softmax_row(S)[k<=q] @ V  - 1e9 * suffixV[q]   (mask AFTER softmax)
// Error budget: threshold 4.1e9 absolute; output ~2e11 from the -1e9 term.
// Pipeline: wtrans -> (xcvt + gemm256<0/2>) x3 -> attn3 (causal flash)
//           -> vscan -> transadd -> gemm256<3>.
// gemm256: 256x256 tile, BK=32, 8 waves, 4-deep LDS ring, counted vmcnt(8),
//          raw s_barrier (no drain), XOR-swizzled LDS rows, and the m201-style
//          2-phase per-K-tile interleave: {ds_read subtile || stage half ->
//          bar -> lgkmcnt(0) -> 16 MFMA -> bar} x2. (T2+T3+T4+T5)

#define Bdim 4
#define Sdim 2048
#define Ddim 2048
#define Hdim 16
#define DHdim 128

typedef __attribute__((ext_vector_type(4))) float f32x4;
typedef __attribute__((ext_vector_type(8))) short s16x8;
typedef __attribute__((ext_vector_type(4))) unsigned short u16x4;
typedef unsigned short u16;

__device__ __forceinline__ u16 f2b(float f) {  // RNE
  union { float f; uint32_t u; } x; x.f = f;
  uint32_t r = x.u + 0x7FFFu + ((x.u >> 16) & 1u);
  return (u16)(r >> 16);
}
__device__ __forceinline__ u16 f2b_rtz(float f) {  // truncate (1 op)
  union { float f; uint32_t u; } x; x.f = f;
  return (u16)(x.u >> 16);
}
__device__ __forceinline__ float b2f(u16 b) {
  union { uint32_t u; float f; } x; x.u = ((uint32_t)b) << 16;
  return x.f;
}
// async global->LDS, 16B/lane; LDS dest = wave-uniform base + lane*16
__device__ __forceinline__ void gl_lds16(const u16* g, u16* l) {
  __builtin_amdgcn_global_load_lds(
      (const __attribute__((address_space(1))) void*)g,
      (__attribute__((address_space(3))) void*)l, 16, 0, 0);
}

// ---------------- 1) transpose + convert weights: WT[n][k] = bf16(W[k][n]) ----
__global__ __launch_bounds__(256) void wtrans_kernel(
    const float* __restrict__ Wq, const float* __restrict__ Wk,
    const float* __restrict__ Wv, const float* __restrict__ Wo,
    u16* __restrict__ WT) {
  __shared__ float tile[64][65];
  const int z = blockIdx.z;
  const float* W = (z == 0) ? Wq : (z == 1) ? Wk : (z == 2) ? Wv : Wo;
  u16* dst = WT + (size_t)z * (size_t)Ddim * Ddim;
  const int kb = blockIdx.x * 64;
  const int nb = blockIdx.y * 64;
  const int c = threadIdx.x & 63;
  const int r4 = threadIdx.x >> 6;
#pragma unroll
  for (int i = 0; i < 16; ++i) {
    int r = r4 * 16 + i;
    tile[r][c] = W[(size_t)(kb + r) * Ddim + nb + c];
  }
  __syncthreads();
#pragma unroll
  for (int i = 0; i < 16; ++i) {
    int r = r4 * 16 + i;
    dst[(size_t)(nb + r) * Ddim + kb + c] = f2b(tile[c][r]);
  }
}

// ---------------- 2a) fp32 -> bf16 (RTZ via v_perm, memory-bound) -----------
__global__ __launch_bounds__(256) void xcvt_kernel(const float* __restrict__ X,
                                                   u16* __restrict__ Xb) {
  const size_t i = ((size_t)blockIdx.x * 256 + threadIdx.x) * 8;
  const uint4 a = *(const uint4*)(X + i);
  const uint4 b = *(const uint4*)(X + i + 4);
  uint4 o;
  o.x = __builtin_amdgcn_perm(a.y, a.x, 0x07060302u);
  o.y = __builtin_amdgcn_perm(a.w, a.z, 0x07060302u);
  o.z = __builtin_amdgcn_perm(b.y, b.x, 0x07060302u);
  o.w = __builtin_amdgcn_perm(b.w, b.z, 0x07060302u);
  *(uint4*)(Xb + i) = o;
}

// ---------------- 2b) 256x256 GEMM: C = A[8192xK] * B^T, K=2048 -------------
// Z=0: head-split u16 out [B,H,S,DH]; Z=2: transposed u16 [B,H,DH,S] (8B
// packed stores); Z=3: fp32 out [M,N].
// 8 waves (2m x 4n), per-wave 128x64 out. LDS ring of 4 K-tiles (BK=32),
// 128 KB. Swizzle: 16B-slot ^= ((row>>1)&3)<<4 (involution; pre-swizzled
// global_load_lds source + swizzled ds_read, rule #21).
// 2 phases per K-tile; vmcnt(8) once per tile (phase 1), never 0 in steady
// state; lgkmcnt(0)+sched_barrier(0) discipline at every phase boundary.
template <int Z>
__global__ __launch_bounds__(512, 2) void gemm256_kernel(
    const u16* __restrict__ A, const u16* __restrict__ Bm,
    const float* __restrict__ bias, void* __restrict__ OutV) {
  __shared__ u16 Asl[4][256 * 32];
  __shared__ u16 Bsl[4][256 * 32];
  const int t = threadIdx.x;
  const int lane = t & 63;
  const int w = t >> 6;            // 0..7
  const int wm = w >> 2, wn = w & 3;
  const int l15 = lane & 15, quad = lane >> 4;
  const int n0 = blockIdx.x * 256;  // bid%8 == n-tile -> per-XCD B-panel reuse
  const int m0 = blockIdx.y * 256;

  // staging geometry: wave w stages rows [w*32, w*32+32) of A and B tiles.
  const int srow = w * 32 + (lane >> 2);
  const int scb = ((((lane & 3) << 4) ^ (((srow >> 1) & 3) << 4)) >> 1);
  const u16* gA = A + (size_t)(m0 + srow) * Ddim + scb;
  const u16* gB = Bm + (size_t)(n0 + srow) * Ddim + scb;
  u16* lA0 = &Asl[0][0] + (w * 32) * 32;  // wave-uniform LDS base
  u16* lB0 = &Bsl[0][0] + (w * 32) * 32;

  // fragment byte offsets (fixed per lane; add buffer base per iteration)
  int aoff[8], boff[4];
#pragma unroll
  for (int mt = 0; mt < 8; ++mt) {
    const int r = wm * 128 + mt * 16 + l15;
    aoff[mt] = r * 64 + ((quad << 4) ^ (((r >> 1) & 3) << 4));
  }
#pragma unroll
  for (int nt = 0; nt < 4; ++nt) {
    const int r = wn * 64 + nt * 16 + l15;
    boff[nt] = r * 64 + ((quad << 4) ^ (((r >> 1) & 3) << 4));
  }
  const f32x4 zero4 = {0.f, 0.f, 0.f, 0.f};
  f32x4 acc[8][4];
#pragma unroll
  for (int i = 0; i < 8; ++i)
#pragma unroll
    for (int j = 0; j < 4; ++j) acc[i][j] = zero4;

  // stage one half (16 rows of A + 16 rows of B) of tile kt_ -> 2 loads/lane
  auto stage_h = [&](int kt_, int buf_, int half_) {
    const size_t ro = (size_t)(half_ * 16) * Ddim;
    gl_lds16(gA + kt_ * 32 + ro, lA0 + buf_ * (256 * 32) + half_ * (16 * 32));
    gl_lds16(gB + kt_ * 32 + ro, lB0 + buf_ * (256 * 32) + half_ * (16 * 32));
  };

  s16x8 af[4], bf[4];
  // phase 0 of tile buf_: read af[0..3],bf[0..3]; MFMA mt 0..3 x nt 0..3
  auto phase0 = [&](int buf_, bool pf_, int ktpf_) {
    const char* ab = (const char*)&Asl[buf_][0];
    const char* bb = (const char*)&Bsl[buf_][0];
#pragma unroll
    for (int mt = 0; mt < 4; ++mt) af[mt] = *(const s16x8*)(ab + aoff[mt]);
#pragma unroll
    for (int nt = 0; nt < 4; ++nt) bf[nt] = *(const s16x8*)(bb + boff[nt]);
    if (pf_) stage_h(ktpf_, ktpf_ & 3, 0);
    __builtin_amdgcn_sched_barrier(0);
    __builtin_amdgcn_s_barrier();
    asm volatile("s_waitcnt lgkmcnt(0)" ::: "memory");
    __builtin_amdgcn_sched_barrier(0);
    __builtin_amdgcn_s_setprio(1);
#pragma unroll
    for (int mt = 0; mt < 4; ++mt)
#pragma unroll
      for (int nt = 0; nt < 4; ++nt)
        acc[mt][nt] = __builtin_amdgcn_mfma_f32_16x16x32_bf16(
            af[mt], bf[nt], acc[mt][nt], 0, 0, 0);
    __builtin_amdgcn_s_setprio(0);
    __builtin_amdgcn_sched_barrier(0);
    __builtin_amdgcn_s_barrier();
  };
  // phase 1 of tile buf_: read af[4..7] (bf reused); vmcnt wait; MFMA mt 4..7
  // VM = counted vmcnt before the barrier (-1 = no wait).
  auto phase1body = [&](int buf_, bool pf_, int ktpf_) {
    const char* ab = (const char*)&Asl[buf_][0];
#pragma unroll
    for (int mt = 0; mt < 4; ++mt) af[mt] = *(const s16x8*)(ab + aoff[4 + mt]);
    if (pf_) stage_h(ktpf_, ktpf_ & 3, 1);
    __builtin_amdgcn_sched_barrier(0);
  };
  auto phase1tail = [&](int buf_) {
    __builtin_amdgcn_s_barrier();
    asm volatile("s_waitcnt lgkmcnt(0)" ::: "memory");
    __builtin_amdgcn_sched_barrier(0);
    __builtin_amdgcn_s_setprio(1);
#pragma unroll
    for (int mt = 0; mt < 4; ++mt)
#pragma unroll
      for (int nt = 0; nt < 4; ++nt)
        acc[4 + mt][nt] = __builtin_amdgcn_mfma_f32_16x16x32_bf16(
            af[mt], bf[nt], acc[4 + mt][nt], 0, 0, 0);
    __builtin_amdgcn_s_setprio(0);
    __builtin_amdgcn_sched_barrier(0);
    __builtin_amdgcn_s_barrier();
  };

  const int NK = Ddim / 32;  // 64
  // prologue: tiles 0,1,2 fully in flight (12 loads); certify tile 0.
  stage_h(0, 0, 0); stage_h(0, 0, 1);
  stage_h(1, 1, 0); stage_h(1, 1, 1);
  stage_h(2, 2, 0); stage_h(2, 2, 1);
  __builtin_amdgcn_sched_barrier(0);
  asm volatile("s_waitcnt vmcnt(8)" ::: "memory");
  __builtin_amdgcn_sched_barrier(0);
  __builtin_amdgcn_s_barrier();
  int kt = 0;
  for (; kt < NK - 3; ++kt) {
    const int buf = kt & 3;
    phase0(buf, true, kt + 3);
    phase1body(buf, true, kt + 3);
    // outstanding: kt+1 (4) + kt+2 (4) + kt+3 (4) = 12 -> tile kt+1 landed
    asm volatile("s_waitcnt vmcnt(8)" ::: "memory");
    __builtin_amdgcn_sched_barrier(0);
    phase1tail(buf);
  }
  // kt = NK-3: outstanding 8; certify tile NK-2.
  phase0(kt & 3, false, 0);
  phase1body(kt & 3, false, 0);
  asm volatile("s_waitcnt vmcnt(4)" ::: "memory");
  __builtin_amdgcn_sched_barrier(0);
  phase1tail(kt & 3);
  ++kt;
  // kt = NK-2: outstanding 4; certify tile NK-1.
  phase0(kt & 3, false, 0);
  phase1body(kt & 3, false, 0);
  asm volatile("s_waitcnt vmcnt(0)" ::: "memory");
  __builtin_amdgcn_sched_barrier(0);
  phase1tail(kt & 3);
  ++kt;
  // kt = NK-1: nothing outstanding.
  phase0(kt & 3, false, 0);
  phase1body(kt & 3, false, 0);
  phase1tail(kt & 3);

  // ---- epilogue ----
  if (Z <= 1) {
    u16* Out = (u16*)OutV;
#pragma unroll
    for (int nt = 0; nt < 4; ++nt) {
      const int gn = n0 + wn * 64 + nt * 16 + l15;
      const float bia = bias[gn];
      const int h = gn >> 7, dh = gn & 127;
#pragma unroll
      for (int mt = 0; mt < 8; ++mt) {
#pragma unroll
        for (int r = 0; r < 4; ++r) {
          const int gm = m0 + wm * 128 + mt * 16 + quad * 4 + r;
          const int b = gm >> 11, s = gm & 2047;
          Out[((size_t)(b * Hdim + h) * Sdim + s) * DHdim + dh] =
              f2b(acc[mt][nt][r] + bia);
        }
      }
    }
  } else if (Z == 2) {
    u16* Out = (u16*)OutV;
#pragma unroll
    for (int nt = 0; nt < 4; ++nt) {
      const int gn = n0 + wn * 64 + nt * 16 + l15;
      const float bia = bias[gn];
      const int h = gn >> 7, dh = gn & 127;
#pragma unroll
      for (int mt = 0; mt < 8; ++mt) {
        const int gm = m0 + wm * 128 + mt * 16 + quad * 4;
        const int b = gm >> 11, s = gm & 2047;
        u16x4 pk;
#pragma unroll
        for (int r = 0; r < 4; ++r) pk[r] = f2b(acc[mt][nt][r] + bia);
        *(u16x4*)(Out + ((size_t)(b * Hdim + h) * DHdim + dh) * Sdim + s) = pk;
      }
    }
  } else {
    float* Out = (float*)OutV;
#pragma unroll
    for (int nt = 0; nt < 4; ++nt) {
      const int gn = n0 + wn * 64 + nt * 16 + l15;
      const float bia = bias[gn];
#pragma unroll
      for (int mt = 0; mt < 8; ++mt) {
#pragma unroll
        for (int r = 0; r < 4; ++r) {
          const int gm = m0 + wm * 128 + mt * 16 + quad * 4 + r;
          Out[(size_t)gm * Ddim + gn] = acc[mt][nt][r] + bia;
        }
      }
    }
  }
}

// ---------------- 3) attention (causal flash, balanced + dbuf + swizzled) ---
#define SCALE2 0.12751744f  // log2(e)/sqrt(128)
__global__ __launch_bounds__(256, 2) void attn3_kernel(
    const u16* __restrict__ Qb, const u16* __restrict__ Kb,
    const u16* __restrict__ Vt, u16* __restrict__ Ao) {
  __shared__ u16 Ks[2][64 * 128];   // 2 x 16 KB
  __shared__ u16 Vs[2][128 * 64];   // 2 x 16 KB
  __shared__ u16 Ps[4][32 * 64];    // 16 KB, per-wave
  const int t = threadIdx.x;
  const int lane = t & 63;
  const int w = t >> 6;
  const int l15 = lane & 15, quad = lane >> 4;
  // XCD-aware swizzle (bijective: 512 = 8*64): XCD n gets bh 8n..8n+7.
  const int bid0 = (int)blockIdx.x + ((int)blockIdx.y << 3);
  const int nbid = (bid0 & 7) * 64 + (bid0 >> 3);
  const int bx = nbid & 7;
  const int bh = nbid >> 3;
  const u16* Kbase = Kb + (size_t)bh * Sdim * DHdim;
  const u16* Vbase = Vt + (size_t)bh * DHdim * Sdim;
  u16* Pw = &Ps[w][0];
  const f32x4 zero4 = {0.f, 0.f, 0.f, 0.f};

  const int klr = lane >> 4;
  const int kcs = (lane & 15) << 4;
  const int vlr = lane >> 3;
  const int vcs = (lane & 7) << 4;

  auto stage = [&](int kt_, int buf_) {
#pragma unroll
    for (int p = 0; p < 4; ++p) {
      const int r = (w << 4) + (p << 2) + klr;
      gl_lds16(Kbase + (((size_t)kt_ * 64 + r) << 7) +
                   ((kcs ^ ((r & 7) << 4)) >> 1),
               &Ks[buf_][(w << 11) + (p << 9)]);
    }
#pragma unroll
    for (int p = 0; p < 4; ++p) {
      const int r = (w << 5) + (p << 3) + vlr;
      gl_lds16(Vbase + (size_t)r * Sdim + kt_ * 64 +
                   ((vcs ^ ((r & 7) << 4)) >> 1),
               &Vs[buf_][(w << 11) + (p << 9)]);
    }
  };

  for (int half = 0; half < 2; ++half) {
    const int qt = half ? bx : 15 - bx;
    const int qw0 = qt * 128 + w * 32;
    const int ktd = qw0 >> 6;
    const bool lowhalf = (qw0 & 63) == 0;
    const int ntiles = qt * 2 + 2;
    const u16* Qp = Qb + ((size_t)bh * Sdim + qw0) * DHdim;
    s16x8 qf[2][4];
#pragma unroll
    for (int mt = 0; mt < 2; ++mt)
#pragma unroll
      for (int ks = 0; ks < 4; ++ks)
        qf[mt][ks] = *(const s16x8*)(Qp + (size_t)(mt * 16 + l15) * DHdim +
                                     ks * 32 + quad * 8);
    f32x4 o1[2][8];
#pragma unroll
    for (int i = 0; i < 2; ++i)
#pragma unroll
      for (int j = 0; j < 8; ++j) o1[i][j] = zero4;
    float lp[2][4];
#pragma unroll
    for (int i = 0; i < 2; ++i)
#pragma unroll
      for (int j = 0; j < 4; ++j) lp[i][j] = 0.f;

    __syncthreads();   // prior readers of LDS done (half=1)
    stage(0, 0);
    __syncthreads();   // vmcnt(0) drain: tile 0 resident
    int cur = 0;
    for (int kt = 0; kt < ntiles; ++kt) {
      if (kt + 1 < ntiles) stage(kt + 1, cur ^ 1);  // async, hidden by compute
      if (kt <= ktd) {
        // ---- QK^T ----
        f32x4 sc[2][4];
#pragma unroll
        for (int i = 0; i < 2; ++i)
#pragma unroll
          for (int j = 0; j < 4; ++j) sc[i][j] = zero4;
#pragma unroll
        for (int ks = 0; ks < 4; ++ks) {
          s16x8 kf[4];
#pragma unroll
          for (int nt = 0; nt < 4; ++nt) {
            const int R = nt * 16 + l15;
            kf[nt] = *(const s16x8*)((const char*)&Ks[cur][0] + (R << 8) +
                                     ((ks * 64 + (quad << 4)) ^
                                      ((R & 7) << 4)));
          }
          __builtin_amdgcn_s_setprio(1);
#pragma unroll
          for (int mt = 0; mt < 2; ++mt)
#pragma unroll
            for (int nt = 0; nt < 4; ++nt)
              sc[mt][nt] = __builtin_amdgcn_mfma_f32_16x16x32_bf16(
                  qf[mt][ks], kf[nt], sc[mt][nt], 0, 0, 0);
          __builtin_amdgcn_s_setprio(0);
        }
        // ---- exp + row-sum partials ----
#pragma unroll
        for (int mt = 0; mt < 2; ++mt)
#pragma unroll
          for (int r = 0; r < 4; ++r) {
            float p0 = exp2f(sc[mt][0][r] * SCALE2);
            float p1 = exp2f(sc[mt][1][r] * SCALE2);
            float p2 = exp2f(sc[mt][2][r] * SCALE2);
            float p3 = exp2f(sc[mt][3][r] * SCALE2);
            sc[mt][0][r] = p0; sc[mt][1][r] = p1;
            sc[mt][2][r] = p2; sc[mt][3][r] = p3;
            lp[mt][r] += (p0 + p1) + (p2 + p3);
          }
        // ---- P store (swizzled) ----
        const bool diag = (kt == ktd);
        if (!diag) {
#pragma unroll
          for (int mt = 0; mt < 2; ++mt)
#pragma unroll
            for (int nt = 0; nt < 4; ++nt)
#pragma unroll
              for (int r = 0; r < 4; ++r) {
                const int row = mt * 16 + quad * 4 + r;
                *(u16*)((char*)Pw + (row << 7) +
                        ((((nt * 16 + l15) << 1)) ^ ((row & 7) << 4))) =
                    f2b_rtz(sc[mt][nt][r]);
              }
        } else {
          const int ntlo = lowhalf ? 0 : 2;
#pragma unroll
          for (int mt = 0; mt < 2; ++mt)
#pragma unroll
            for (int nt = 0; nt < 4; ++nt) {
              if (!lowhalf && nt < 2) {
#pragma unroll
                for (int r = 0; r < 4; ++r) {
                  const int row = mt * 16 + quad * 4 + r;
                  *(u16*)((char*)Pw + (row << 7) +
                          ((((nt * 16 + l15) << 1)) ^ ((row & 7) << 4))) =
                      f2b_rtz(sc[mt][nt][r]);
                }
              } else if (nt >= ntlo && nt < ntlo + 2) {
                const int kg = kt * 64 + nt * 16 + l15;
#pragma unroll
                for (int r = 0; r < 4; ++r) {
                  const int qg = qw0 + mt * 16 + quad * 4 + r;
                  const int row = mt * 16 + quad * 4 + r;
                  *(u16*)((char*)Pw + (row << 7) +
                          ((((nt * 16 + l15) << 1)) ^ ((row & 7) << 4))) =
                      (kg > qg) ? (u16)0 : f2b_rtz(sc[mt][nt][r]);
                }
              }
            }
        }
        // ---- PV ----
        const int k2max = (diag && lowhalf) ? 1 : 2;
#pragma unroll
        for (int k2 = 0; k2 < 2; ++k2) {
          if (k2 >= k2max) break;
          s16x8 pf[2];
#pragma unroll
          for (int mt = 0; mt < 2; ++mt) {
            const int R = mt * 16 + l15;
            pf[mt] = *(const s16x8*)((const char*)Pw + (R << 7) +
                                     ((k2 * 64 + (quad << 4)) ^
                                      ((R & 7) << 4)));
          }
          __builtin_amdgcn_s_setprio(1);
#pragma unroll
          for (int nt = 0; nt < 8; ++nt) {
            const int R = nt * 16 + l15;
            const s16x8 vf = *(const s16x8*)(
                (const char*)&Vs[cur][0] + (R << 7) +
                ((k2 * 64 + (quad << 4)) ^ ((R & 7) << 4)));
#pragma unroll
            for (int mt = 0; mt < 2; ++mt)
              o1[mt][nt] = __builtin_amdgcn_mfma_f32_16x16x32_bf16(
                  pf[mt], vf, o1[mt][nt], 0, 0, 0);
          }
          __builtin_amdgcn_s_setprio(0);
        }
      }
      __syncthreads();  // readers of buf done + next tile's stage arrived
      cur ^= 1;
    }
    // ---- epilogue ----
    const int b = bh >> 4, h = bh & 15;
#pragma unroll
    for (int mt = 0; mt < 2; ++mt) {
#pragma unroll
      for (int r = 0; r < 4; ++r) {
        float l = lp[mt][r];
        l += __shfl_xor(l, 1);
        l += __shfl_xor(l, 2);
        l += __shfl_xor(l, 4);
        l += __shfl_xor(l, 8);
        const float invl = 1.0f / l;
        const int sq = qw0 + mt * 16 + quad * 4 + r;
        const size_t rowb = ((size_t)b * Sdim + sq) * Ddim + h * DHdim;
#pragma unroll
        for (int nt = 0; nt < 8; ++nt)
          Ao[rowb + nt * 16 + l15] = f2b(o1[mt][nt][r] * invl);
      }
    }
  }
}

// ---------------- 4) suffix scan of V: Vsuf[bh][dh][q] = fp16(sum_{k>q} V) --
__global__ __launch_bounds__(256) void vscan_kernel(const u16* __restrict__ Vt,
                                                    u16* __restrict__ Vsuf) {
  const int t = threadIdx.x, lane = t & 63, w = t >> 6;
  const int idx = blockIdx.x * 4 + w;  // bh*128 + dh
  const u16* src = Vt + (size_t)idx * Sdim;
  u16* dst = Vsuf + (size_t)idx * Sdim;
  const int c0 = lane * 32;
  float v[32];
#pragma unroll
  for (int p = 0; p < 4; ++p) {
    uint4 raw = *(const uint4*)(src + c0 + p * 8);
    const u16* rp = (const u16*)&raw;
#pragma unroll
    for (int j = 0; j < 8; ++j) v[p * 8 + j] = b2f(rp[j]);
  }
  float tot = 0.f;
#pragma unroll
  for (int j = 0; j < 32; ++j) tot += v[j];
  float T = tot;
#pragma unroll
  for (int off = 1; off < 64; off <<= 1) {
    float u = __shfl_down(T, off);
    if (lane + off < 64) T += u;
  }
  float s = T - tot;
  u16 outv[32];
#pragma unroll
  for (int j = 31; j >= 0; --j) {
    outv[j] = __half_as_ushort(__float2half(s));
    s += v[j];
  }
#pragma unroll
  for (int p = 0; p < 4; ++p)
    *(uint4*)(dst + c0 + p * 8) = *(uint4*)(outv + p * 8);
}

// ---------------- 5) Ao[b][q][h,dh] -= 1e9 * Vsuf[bh][dh][q] (transpose) ----
__global__ __launch_bounds__(256) void transadd_kernel(
    const u16* __restrict__ Vsuf, u16* __restrict__ Ao) {
  __shared__ float tile[64][65];
  const int qt = blockIdx.x;
  const int dt = blockIdx.y;
  const int bh = blockIdx.z;
  const int t = threadIdx.x;
  const int r = t >> 2, c0 = (t & 3) * 16;
  const u16* sp =
      Vsuf + ((size_t)bh * 128 + dt * 64 + r) * Sdim + qt * 64 + c0;
#pragma unroll
  for (int h2 = 0; h2 < 2; ++h2) {
    uint4 raw = *(const uint4*)(sp + h2 * 8);
    const u16* rp = (const u16*)&raw;
#pragma unroll
    for (int j = 0; j < 8; ++j)
      tile[c0 + h2 * 8 + j][r] = __half2float(__ushort_as_half(rp[j]));
  }
  __syncthreads();
  const int b = bh >> 4, h = bh & 15;
  u16* ap =
      Ao + ((size_t)b * Sdim + qt * 64 + r) * Ddim + h * 128 + dt * 64 + c0;
#pragma unroll
  for (int h2 = 0; h2 < 2; ++h2) {
    uint4 raw = *(uint4*)(ap + h2 * 8);
    u16* rp = (u16*)&raw;
#pragma unroll
    for (int j = 0; j < 8; ++j) {
      float a = b2f(rp[j]) - 1e9f * tile[r][c0 + h2 * 8 + j];
      rp[j] = f2b(a);
    }
    *(uint4*)(ap + h2 * 8) = raw;
  }
}

// ---------------- launcher ---------------------------------------------------
extern "C" void kernel_launch(void* const* d_in, const int* in_sizes, int n_in,
                              void* d_out, int out_size, void* d_ws,
                              size_t ws_size, hipStream_t stream) {
  (void)in_sizes; (void)n_in; (void)out_size; (void)ws_size;
  const float* q = (const float*)d_in[0];
  const float* k = (const float*)d_in[1];
  const float* v = (const float*)d_in[2];
  const float* Wq = (const float*)d_in[3];
  const float* bq = (const float*)d_in[4];
  const float* Wk = (const float*)d_in[5];
  const float* bk = (const float*)d_in[6];
  const float* Wv = (const float*)d_in[7];
  const float* bv = (const float*)d_in[8];
  const float* Wo = (const float*)d_in[9];
  const float* bo = (const float*)d_in[10];
  float* out = (float*)d_out;
  char* ws = (char*)d_ws;
  // ws: WT 33.5M | Qb 33.5M (Vsuf later) | Kb | Vt | Xb 33.5M (Ao later)
  u16* WT = (u16*)(ws);
  u16* Qb = (u16*)(ws + 33554432);
  u16* Kb = (u16*)(ws + 67108864);
  u16* Vt = (u16*)(ws + 100663296);
  u16* Xb = (u16*)(ws + 134217728);  // scratch for bf16 inputs (pre-attn)
  u16* Ao = Xb;                       // Xb dead after gemms
  u16* WoT = WT + (size_t)3 * Ddim * Ddim;
  u16* Vsuf = Qb;                     // Qb dead after attn3

  wtrans_kernel<<<dim3(32, 32, 4), dim3(256), 0, stream>>>(Wq, Wk, Wv, Wo, WT);
  const float* Xs[3] = {q, k, v};
  const float* bs[3] = {bq, bk, bv};
  for (int z = 0; z < 3; ++z) {
    xcvt_kernel<<<dim3(8192), dim3(256), 0, stream>>>(Xs[z], Xb);
    if (z < 2)
      gemm256_kernel<0><<<dim3(8, 32), dim3(512), 0, stream>>>(
          Xb, WT + (size_t)z * Ddim * Ddim, bs[z], (z == 0) ? Qb : Kb);
    else
      gemm256_kernel<2><<<dim3(8, 32), dim3(512), 0, stream>>>(
          Xb, WT + (size_t)2 * Ddim * Ddim, bs[2], Vt);
  }
  attn3_kernel<<<dim3(8, 64), dim3(256), 0, stream>>>(Qb, Kb, Vt, Ao);
  vscan_kernel<<<dim3(2048), dim3(256), 0, stream>>>(Vt, Vsuf);
  transadd_kernel<<<dim3(32, 2, 64), dim3(256), 0, stream>>>(Vsuf, Ao);
  gemm256_kernel<3><<<dim3(8, 32), dim3(512), 0, stream>>>(Ao, WoT, bo, out);
}

// Round 5
// 731.253 us; speedup vs baseline: 1.5228x; 1.0273x over previous
//
#include <hip/hip_runtime.h>
#include <hip/hip_bf16.h>
#include <hip/hip_fp16.h>
#include <stdint.h>

// MultiHeadSelfAttention: B=4 S=2048 D=2048 H=16 DH=128, fp32 in/out.
// out[q] = softmax_row(S)[k<=q] @ V  - 1e9 * suffixV[q]   (mask AFTER softmax)
// Error budget: threshold 4.1e9 absolute; output ~2e11 from the -1e9 term.
// Pipeline: wtrans -> (xcvt + gemm128<0/2>) x3 -> attn3 (causal flash)
//           -> vscan -> transadd -> gemm128<3>.
// gemm128: 128x256 tile, BK=32, 8 waves (64x64/wave), 3-deep LDS ring (72 KB
//          -> 2 blocks/CU for TLP stall-covering), counted vmcnt(3), ONE raw
//          s_barrier per K-tile, XOR-swizzled LDS rows (T1+T2+T4).

#define Bdim 4
#define Sdim 2048
#define Ddim 2048
#define Hdim 16
#define DHdim 128

typedef __attribute__((ext_vector_type(4))) float f32x4;
typedef __attribute__((ext_vector_type(8))) short s16x8;
typedef __attribute__((ext_vector_type(4))) unsigned short u16x4;
typedef unsigned short u16;

__device__ __forceinline__ u16 f2b(float f) {  // RNE
  union { float f; uint32_t u; } x; x.f = f;
  uint32_t r = x.u + 0x7FFFu + ((x.u >> 16) & 1u);
  return (u16)(r >> 16);
}
__device__ __forceinline__ u16 f2b_rtz(float f) {  // truncate (1 op)
  union { float f; uint32_t u; } x; x.f = f;
  return (u16)(x.u >> 16);
}
__device__ __forceinline__ float b2f(u16 b) {
  union { uint32_t u; float f; } x; x.u = ((uint32_t)b) << 16;
  return x.f;
}
// async global->LDS, 16B/lane; LDS dest = wave-uniform base + lane*16
__device__ __forceinline__ void gl_lds16(const u16* g, u16* l) {
  __builtin_amdgcn_global_load_lds(
      (const __attribute__((address_space(1))) void*)g,
      (__attribute__((address_space(3))) void*)l, 16, 0, 0);
}

// ---------------- 1) transpose + convert weights: WT[n][k] = bf16(W[k][n]) ----
__global__ __launch_bounds__(256) void wtrans_kernel(
    const float* __restrict__ Wq, const float* __restrict__ Wk,
    const float* __restrict__ Wv, const float* __restrict__ Wo,
    u16* __restrict__ WT) {
  __shared__ float tile[64][65];
  const int z = blockIdx.z;
  const float* W = (z == 0) ? Wq : (z == 1) ? Wk : (z == 2) ? Wv : Wo;
  u16* dst = WT + (size_t)z * (size_t)Ddim * Ddim;
  const int kb = blockIdx.x * 64;
  const int nb = blockIdx.y * 64;
  const int c = threadIdx.x & 63;
  const int r4 = threadIdx.x >> 6;
#pragma unroll
  for (int i = 0; i < 16; ++i) {
    int r = r4 * 16 + i;
    tile[r][c] = W[(size_t)(kb + r) * Ddim + nb + c];
  }
  __syncthreads();
#pragma unroll
  for (int i = 0; i < 16; ++i) {
    int r = r4 * 16 + i;
    dst[(size_t)(nb + r) * Ddim + kb + c] = f2b(tile[c][r]);
  }
}

// ---------------- 2a) fp32 -> bf16 (RTZ via v_perm, memory-bound) -----------
__global__ __launch_bounds__(256) void xcvt_kernel(const float* __restrict__ X,
                                                   u16* __restrict__ Xb) {
  const size_t i = ((size_t)blockIdx.x * 256 + threadIdx.x) * 8;
  const uint4 a = *(const uint4*)(X + i);
  const uint4 b = *(const uint4*)(X + i + 4);
  uint4 o;
  o.x = __builtin_amdgcn_perm(a.y, a.x, 0x07060302u);
  o.y = __builtin_amdgcn_perm(a.w, a.z, 0x07060302u);
  o.z = __builtin_amdgcn_perm(b.y, b.x, 0x07060302u);
  o.w = __builtin_amdgcn_perm(b.w, b.z, 0x07060302u);
  *(uint4*)(Xb + i) = o;
}

// ---------------- 2b) 128x256 GEMM: C = A[8192xK] * B^T, K=2048 -------------
// Z=0: head-split u16 out [B,H,S,DH]; Z=2: transposed u16 [B,H,DH,S] (8B
// packed stores); Z=3: fp32 out [M,N].
// 8 waves (2m x 4n), per-wave 64x64 out (acc 4x4). LDS ring of 3 K-tiles
// (BK=32) = 72 KB -> 2 blocks/CU. Swizzle: 16B-slot ^= ((row>>1)&3)
// (involution; pre-swizzled global_load_lds source + swizzled ds_read).
// One s_barrier + one counted vmcnt(3) per K-tile; ds_read->MFMA waits left
// to the compiler (fine-grained lgkmcnt).
template <int Z>
__global__ __launch_bounds__(512, 4) void gemm128_kernel(
    const u16* __restrict__ A, const u16* __restrict__ Bm,
    const float* __restrict__ bias, void* __restrict__ OutV) {
  __shared__ u16 Asl[3][128 * 32];  // 3 x 8 KB
  __shared__ u16 Bsl[3][256 * 32];  // 3 x 16 KB
  const int t = threadIdx.x;
  const int lane = t & 63;
  const int w = t >> 6;            // 0..7
  const int wm = w >> 2, wn = w & 3;
  const int l15 = lane & 15, quad = lane >> 4;
  const int n0 = blockIdx.x * 256;  // bid%8 == n-tile -> per-XCD B-panel reuse
  const int m0 = blockIdx.y * 128;

  // staging geometry: wave w stages A rows [w*16,w*16+16) (1 load/lane) and
  // B rows [w*32,w*32+32) (2 loads/lane). Source pre-swizzled so linear LDS
  // dest + swizzled ds_read compose to identity (rule #21).
  const int srA = w * 16 + (lane >> 2);
  const int srB = w * 32 + (lane >> 2);  // and +16 (same swz: (r>>1)&3 equal)
  const int scA = ((((lane & 3) << 4) ^ (((srA >> 1) & 3) << 4)) >> 1);
  const int scB = ((((lane & 3) << 4) ^ (((srB >> 1) & 3) << 4)) >> 1);
  const u16* gA = A + (size_t)(m0 + srA) * Ddim + scA;
  const u16* gB0 = Bm + (size_t)(n0 + srB) * Ddim + scB;
  const u16* gB1 = gB0 + (size_t)16 * Ddim;
  u16* ldA = &Asl[0][0] + w * (16 * 32);   // wave-uniform LDS bases (buf 0)
  u16* ldB = &Bsl[0][0] + w * (32 * 32);

  // fragment byte offsets (fixed per lane; add buffer base per iteration)
  int aoff[4], boff[4];
#pragma unroll
  for (int mt = 0; mt < 4; ++mt) {
    const int r = wm * 64 + mt * 16 + l15;
    aoff[mt] = r * 64 + ((quad << 4) ^ (((r >> 1) & 3) << 4));
  }
#pragma unroll
  for (int nt = 0; nt < 4; ++nt) {
    const int r = wn * 64 + nt * 16 + l15;
    boff[nt] = r * 64 + ((quad << 4) ^ (((r >> 1) & 3) << 4));
  }
  const f32x4 zero4 = {0.f, 0.f, 0.f, 0.f};
  f32x4 acc[4][4];
#pragma unroll
  for (int i = 0; i < 4; ++i)
#pragma unroll
    for (int j = 0; j < 4; ++j) acc[i][j] = zero4;

  // stage tile at current gA/gB pointers into ring buffer buf_ (3 gl_lds),
  // then advance pointers by one K-tile.
  auto stage = [&]() {
    // buffer index advances with the pointers; caller passes LDS bases.
  };
  (void)stage;

  const int NK = Ddim / 32;  // 64

#define STAGE(buf_)                                             \
  do {                                                          \
    gl_lds16(gA, ldA + (buf_) * (128 * 32));                    \
    gl_lds16(gB0, ldB + (buf_) * (256 * 32));                   \
    gl_lds16(gB1, ldB + (buf_) * (256 * 32) + 16 * 32);         \
    gA += 32; gB0 += 32; gB1 += 32;                             \
  } while (0)

#define COMPUTE(buf_)                                                       \
  do {                                                                      \
    const char* ab = (const char*)&Asl[(buf_)][0];                          \
    const char* bb = (const char*)&Bsl[(buf_)][0];                          \
    s16x8 af[4], bf[4];                                                     \
    _Pragma("unroll") for (int mt = 0; mt < 4; ++mt)                        \
        af[mt] = *(const s16x8*)(ab + aoff[mt]);                            \
    _Pragma("unroll") for (int nt = 0; nt < 4; ++nt)                        \
        bf[nt] = *(const s16x8*)(bb + boff[nt]);                            \
    __builtin_amdgcn_s_setprio(1);                                          \
    _Pragma("unroll") for (int mt = 0; mt < 4; ++mt)                        \
        _Pragma("unroll") for (int nt = 0; nt < 4; ++nt)                    \
            acc[mt][nt] = __builtin_amdgcn_mfma_f32_16x16x32_bf16(          \
                af[mt], bf[nt], acc[mt][nt], 0, 0, 0);                      \
    __builtin_amdgcn_s_setprio(0);                                          \
  } while (0)

  // prologue: tiles 0,1 in flight (6 loads); certify tile 0.
  STAGE(0);
  STAGE(1);
  asm volatile("s_waitcnt vmcnt(3)" ::: "memory");
  __builtin_amdgcn_sched_barrier(0);
  __builtin_amdgcn_s_barrier();
  int cur = 0;
  for (int kt = 0; kt < NK - 2; ++kt) {
    int sb = cur - 1; if (sb < 0) sb = 2;   // (cur+2)%3
    STAGE(sb);                               // issue-early: next-next tile
    COMPUTE(cur);                            // compiler-scheduled lgkmcnt
    asm volatile("s_waitcnt vmcnt(3)" ::: "memory");  // tile kt+1 landed
    __builtin_amdgcn_sched_barrier(0);
    __builtin_amdgcn_s_barrier();
    if (++cur == 3) cur = 0;
  }
  // kt = NK-2: outstanding 3 (tile NK-1); certify it.
  COMPUTE(cur);
  asm volatile("s_waitcnt vmcnt(0)" ::: "memory");
  __builtin_amdgcn_sched_barrier(0);
  __builtin_amdgcn_s_barrier();
  if (++cur == 3) cur = 0;
  // kt = NK-1: compute only.
  COMPUTE(cur);
#undef STAGE
#undef COMPUTE

  // ---- epilogue ----
  if (Z <= 1) {
    u16* Out = (u16*)OutV;
#pragma unroll
    for (int nt = 0; nt < 4; ++nt) {
      const int gn = n0 + wn * 64 + nt * 16 + l15;
      const float bia = bias[gn];
      const int h = gn >> 7, dh = gn & 127;
#pragma unroll
      for (int mt = 0; mt < 4; ++mt) {
#pragma unroll
        for (int r = 0; r < 4; ++r) {
          const int gm = m0 + wm * 64 + mt * 16 + quad * 4 + r;
          const int b = gm >> 11, s = gm & 2047;
          Out[((size_t)(b * Hdim + h) * Sdim + s) * DHdim + dh] =
              f2b(acc[mt][nt][r] + bia);
        }
      }
    }
  } else if (Z == 2) {
    u16* Out = (u16*)OutV;
#pragma unroll
    for (int nt = 0; nt < 4; ++nt) {
      const int gn = n0 + wn * 64 + nt * 16 + l15;
      const float bia = bias[gn];
      const int h = gn >> 7, dh = gn & 127;
#pragma unroll
      for (int mt = 0; mt < 4; ++mt) {
        const int gm = m0 + wm * 64 + mt * 16 + quad * 4;
        const int b = gm >> 11, s = gm & 2047;
        u16x4 pk;
#pragma unroll
        for (int r = 0; r < 4; ++r) pk[r] = f2b(acc[mt][nt][r] + bia);
        *(u16x4*)(Out + ((size_t)(b * Hdim + h) * DHdim + dh) * Sdim + s) = pk;
      }
    }
  } else {
    float* Out = (float*)OutV;
#pragma unroll
    for (int nt = 0; nt < 4; ++nt) {
      const int gn = n0 + wn * 64 + nt * 16 + l15;
      const float bia = bias[gn];
#pragma unroll
      for (int mt = 0; mt < 4; ++mt) {
#pragma unroll
        for (int r = 0; r < 4; ++r) {
          const int gm = m0 + wm * 64 + mt * 16 + quad * 4 + r;
          Out[(size_t)gm * Ddim + gn] = acc[mt][nt][r] + bia;
        }
      }
    }
  }
}

// ---------------- 3) attention (causal flash, balanced + dbuf + swizzled) ---
#define SCALE2 0.12751744f  // log2(e)/sqrt(128)
__global__ __launch_bounds__(256, 2) void attn3_kernel(
    const u16* __restrict__ Qb, const u16* __restrict__ Kb,
    const u16* __restrict__ Vt, u16* __restrict__ Ao) {
  __shared__ u16 Ks[2][64 * 128];   // 2 x 16 KB
  __shared__ u16 Vs[2][128 * 64];   // 2 x 16 KB
  __shared__ u16 Ps[4][32 * 64];    // 16 KB, per-wave
  const int t = threadIdx.x;
  const int lane = t & 63;
  const int w = t >> 6;
  const int l15 = lane & 15, quad = lane >> 4;
  // XCD-aware swizzle (bijective: 512 = 8*64): XCD n gets bh 8n..8n+7.
  const int bid0 = (int)blockIdx.x + ((int)blockIdx.y << 3);
  const int nbid = (bid0 & 7) * 64 + (bid0 >> 3);
  const int bx = nbid & 7;
  const int bh = nbid >> 3;
  const u16* Kbase = Kb + (size_t)bh * Sdim * DHdim;
  const u16* Vbase = Vt + (size_t)bh * DHdim * Sdim;
  u16* Pw = &Ps[w][0];
  const f32x4 zero4 = {0.f, 0.f, 0.f, 0.f};

  const int klr = lane >> 4;
  const int kcs = (lane & 15) << 4;
  const int vlr = lane >> 3;
  const int vcs = (lane & 7) << 4;

  auto stage = [&](int kt_, int buf_) {
#pragma unroll
    for (int p = 0; p < 4; ++p) {
      const int r = (w << 4) + (p << 2) + klr;
      gl_lds16(Kbase + (((size_t)kt_ * 64 + r) << 7) +
                   ((kcs ^ ((r & 7) << 4)) >> 1),
               &Ks[buf_][(w << 11) + (p << 9)]);
    }
#pragma unroll
    for (int p = 0; p < 4; ++p) {
      const int r = (w << 5) + (p << 3) + vlr;
      gl_lds16(Vbase + (size_t)r * Sdim + kt_ * 64 +
                   ((vcs ^ ((r & 7) << 4)) >> 1),
               &Vs[buf_][(w << 11) + (p << 9)]);
    }
  };

  for (int half = 0; half < 2; ++half) {
    const int qt = half ? bx : 15 - bx;
    const int qw0 = qt * 128 + w * 32;
    const int ktd = qw0 >> 6;
    const bool lowhalf = (qw0 & 63) == 0;
    const int ntiles = qt * 2 + 2;
    const u16* Qp = Qb + ((size_t)bh * Sdim + qw0) * DHdim;
    s16x8 qf[2][4];
#pragma unroll
    for (int mt = 0; mt < 2; ++mt)
#pragma unroll
      for (int ks = 0; ks < 4; ++ks)
        qf[mt][ks] = *(const s16x8*)(Qp + (size_t)(mt * 16 + l15) * DHdim +
                                     ks * 32 + quad * 8);
    f32x4 o1[2][8];
#pragma unroll
    for (int i = 0; i < 2; ++i)
#pragma unroll
      for (int j = 0; j < 8; ++j) o1[i][j] = zero4;
    float lp[2][4];
#pragma unroll
    for (int i = 0; i < 2; ++i)
#pragma unroll
      for (int j = 0; j < 4; ++j) lp[i][j] = 0.f;

    __syncthreads();   // prior readers of LDS done (half=1)
    stage(0, 0);
    __syncthreads();   // vmcnt(0) drain: tile 0 resident
    int cur = 0;
    for (int kt = 0; kt < ntiles; ++kt) {
      if (kt + 1 < ntiles) stage(kt + 1, cur ^ 1);  // async, hidden by compute
      if (kt <= ktd) {
        // ---- QK^T ----
        f32x4 sc[2][4];
#pragma unroll
        for (int i = 0; i < 2; ++i)
#pragma unroll
          for (int j = 0; j < 4; ++j) sc[i][j] = zero4;
#pragma unroll
        for (int ks = 0; ks < 4; ++ks) {
          s16x8 kf[4];
#pragma unroll
          for (int nt = 0; nt < 4; ++nt) {
            const int R = nt * 16 + l15;
            kf[nt] = *(const s16x8*)((const char*)&Ks[cur][0] + (R << 8) +
                                     ((ks * 64 + (quad << 4)) ^
                                      ((R & 7) << 4)));
          }
          __builtin_amdgcn_s_setprio(1);
#pragma unroll
          for (int mt = 0; mt < 2; ++mt)
#pragma unroll
            for (int nt = 0; nt < 4; ++nt)
              sc[mt][nt] = __builtin_amdgcn_mfma_f32_16x16x32_bf16(
                  qf[mt][ks], kf[nt], sc[mt][nt], 0, 0, 0);
          __builtin_amdgcn_s_setprio(0);
        }
        // ---- exp + row-sum partials ----
#pragma unroll
        for (int mt = 0; mt < 2; ++mt)
#pragma unroll
          for (int r = 0; r < 4; ++r) {
            float p0 = exp2f(sc[mt][0][r] * SCALE2);
            float p1 = exp2f(sc[mt][1][r] * SCALE2);
            float p2 = exp2f(sc[mt][2][r] * SCALE2);
            float p3 = exp2f(sc[mt][3][r] * SCALE2);
            sc[mt][0][r] = p0; sc[mt][1][r] = p1;
            sc[mt][2][r] = p2; sc[mt][3][r] = p3;
            lp[mt][r] += (p0 + p1) + (p2 + p3);
          }
        // ---- P store (swizzled) ----
        const bool diag = (kt == ktd);
        if (!diag) {
#pragma unroll
          for (int mt = 0; mt < 2; ++mt)
#pragma unroll
            for (int nt = 0; nt < 4; ++nt)
#pragma unroll
              for (int r = 0; r < 4; ++r) {
                const int row = mt * 16 + quad * 4 + r;
                *(u16*)((char*)Pw + (row << 7) +
                        ((((nt * 16 + l15) << 1)) ^ ((row & 7) << 4))) =
                    f2b_rtz(sc[mt][nt][r]);
              }
        } else {
          const int ntlo = lowhalf ? 0 : 2;
#pragma unroll
          for (int mt = 0; mt < 2; ++mt)
#pragma unroll
            for (int nt = 0; nt < 4; ++nt) {
              if (!lowhalf && nt < 2) {
#pragma unroll
                for (int r = 0; r < 4; ++r) {
                  const int row = mt * 16 + quad * 4 + r;
                  *(u16*)((char*)Pw + (row << 7) +
                          ((((nt * 16 + l15) << 1)) ^ ((row & 7) << 4))) =
                      f2b_rtz(sc[mt][nt][r]);
                }
              } else if (nt >= ntlo && nt < ntlo + 2) {
                const int kg = kt * 64 + nt * 16 + l15;
#pragma unroll
                for (int r = 0; r < 4; ++r) {
                  const int qg = qw0 + mt * 16 + quad * 4 + r;
                  const int row = mt * 16 + quad * 4 + r;
                  *(u16*)((char*)Pw + (row << 7) +
                          ((((nt * 16 + l15) << 1)) ^ ((row & 7) << 4))) =
                      (kg > qg) ? (u16)0 : f2b_rtz(sc[mt][nt][r]);
                }
              }
            }
        }
        // ---- PV ----
        const int k2max = (diag && lowhalf) ? 1 : 2;
#pragma unroll
        for (int k2 = 0; k2 < 2; ++k2) {
          if (k2 >= k2max) break;
          s16x8 pf[2];
#pragma unroll
          for (int mt = 0; mt < 2; ++mt) {
            const int R = mt * 16 + l15;
            pf[mt] = *(const s16x8*)((const char*)Pw + (R << 7) +
                                     ((k2 * 64 + (quad << 4)) ^
                                      ((R & 7) << 4)));
          }
          __builtin_amdgcn_s_setprio(1);
#pragma unroll
          for (int nt = 0; nt < 8; ++nt) {
            const int R = nt * 16 + l15;
            const s16x8 vf = *(const s16x8*)(
                (const char*)&Vs[cur][0] + (R << 7) +
                ((k2 * 64 + (quad << 4)) ^ ((R & 7) << 4)));
#pragma unroll
            for (int mt = 0; mt < 2; ++mt)
              o1[mt][nt] = __builtin_amdgcn_mfma_f32_16x16x32_bf16(
                  pf[mt], vf, o1[mt][nt], 0, 0, 0);
          }
          __builtin_amdgcn_s_setprio(0);
        }
      }
      __syncthreads();  // readers of buf done + next tile's stage arrived
      cur ^= 1;
    }
    // ---- epilogue ----
    const int b = bh >> 4, h = bh & 15;
#pragma unroll
    for (int mt = 0; mt < 2; ++mt) {
#pragma unroll
      for (int r = 0; r < 4; ++r) {
        float l = lp[mt][r];
        l += __shfl_xor(l, 1);
        l += __shfl_xor(l, 2);
        l += __shfl_xor(l, 4);
        l += __shfl_xor(l, 8);
        const float invl = 1.0f / l;
        const int sq = qw0 + mt * 16 + quad * 4 + r;
        const size_t rowb = ((size_t)b * Sdim + sq) * Ddim + h * DHdim;
#pragma unroll
        for (int nt = 0; nt < 8; ++nt)
          Ao[rowb + nt * 16 + l15] = f2b(o1[mt][nt][r] * invl);
      }
    }
  }
}

// ---------------- 4) suffix scan of V: Vsuf[bh][dh][q] = fp16(sum_{k>q} V) --
__global__ __launch_bounds__(256) void vscan_kernel(const u16* __restrict__ Vt,
                                                    u16* __restrict__ Vsuf) {
  const int t = threadIdx.x, lane = t & 63, w = t >> 6;
  const int idx = blockIdx.x * 4 + w;  // bh*128 + dh
  const u16* src = Vt + (size_t)idx * Sdim;
  u16* dst = Vsuf + (size_t)idx * Sdim;
  const int c0 = lane * 32;
  float v[32];
#pragma unroll
  for (int p = 0; p < 4; ++p) {
    uint4 raw = *(const uint4*)(src + c0 + p * 8);
    const u16* rp = (const u16*)&raw;
#pragma unroll
    for (int j = 0; j < 8; ++j) v[p * 8 + j] = b2f(rp[j]);
  }
  float tot = 0.f;
#pragma unroll
  for (int j = 0; j < 32; ++j) tot += v[j];
  float T = tot;
#pragma unroll
  for (int off = 1; off < 64; off <<= 1) {
    float u = __shfl_down(T, off);
    if (lane + off < 64) T += u;
  }
  float s = T - tot;
  u16 outv[32];
#pragma unroll
  for (int j = 31; j >= 0; --j) {
    outv[j] = __half_as_ushort(__float2half(s));
    s += v[j];
  }
#pragma unroll
  for (int p = 0; p < 4; ++p)
    *(uint4*)(dst + c0 + p * 8) = *(uint4*)(outv + p * 8);
}

// ---------------- 5) Ao[b][q][h,dh] -= 1e9 * Vsuf[bh][dh][q] (transpose) ----
__global__ __launch_bounds__(256) void transadd_kernel(
    const u16* __restrict__ Vsuf, u16* __restrict__ Ao) {
  __shared__ float tile[64][65];
  const int qt = blockIdx.x;
  const int dt = blockIdx.y;
  const int bh = blockIdx.z;
  const int t = threadIdx.x;
  const int r = t >> 2, c0 = (t & 3) * 16;
  const u16* sp =
      Vsuf + ((size_t)bh * 128 + dt * 64 + r) * Sdim + qt * 64 + c0;
#pragma unroll
  for (int h2 = 0; h2 < 2; ++h2) {
    uint4 raw = *(const uint4*)(sp + h2 * 8);
    const u16* rp = (const u16*)&raw;
#pragma unroll
    for (int j = 0; j < 8; ++j)
      tile[c0 + h2 * 8 + j][r] = __half2float(__ushort_as_half(rp[j]));
  }
  __syncthreads();
  const int b = bh >> 4, h = bh & 15;
  u16* ap =
      Ao + ((size_t)b * Sdim + qt * 64 + r) * Ddim + h * 128 + dt * 64 + c0;
#pragma unroll
  for (int h2 = 0; h2 < 2; ++h2) {
    uint4 raw = *(uint4*)(ap + h2 * 8);
    u16* rp = (u16*)&raw;
#pragma unroll
    for (int j = 0; j < 8; ++j) {
      float a = b2f(rp[j]) - 1e9f * tile[r][c0 + h2 * 8 + j];
      rp[j] = f2b(a);
    }
    *(uint4*)(ap + h2 * 8) = raw;
  }
}

// ---------------- launcher ---------------------------------------------------
extern "C" void kernel_launch(void* const* d_in, const int* in_sizes, int n_in,
                              void* d_out, int out_size, void* d_ws,
                              size_t ws_size, hipStream_t stream) {
  (void)in_sizes; (void)n_in; (void)out_size; (void)ws_size;
  const float* q = (const float*)d_in[0];
  const float* k = (const float*)d_in[1];
  const float* v = (const float*)d_in[2];
  const float* Wq = (const float*)d_in[3];
  const float* bq = (const float*)d_in[4];
  const float* Wk = (const float*)d_in[5];
  const float* bk = (const float*)d_in[6];
  const float* Wv = (const float*)d_in[7];
  const float* bv = (const float*)d_in[8];
  const float* Wo = (const float*)d_in[9];
  const float* bo = (const float*)d_in[10];
  float* out = (float*)d_out;
  char* ws = (char*)d_ws;
  // ws: WT 33.5M | Qb 33.5M (Vsuf later) | Kb | Vt | Xb 33.5M (Ao later)
  u16* WT = (u16*)(ws);
  u16* Qb = (u16*)(ws + 33554432);
  u16* Kb = (u16*)(ws + 67108864);
  u16* Vt = (u16*)(ws + 100663296);
  u16* Xb = (u16*)(ws + 134217728);  // scratch for bf16 inputs (pre-attn)
  u16* Ao = Xb;                       // Xb dead after gemms
  u16* WoT = WT + (size_t)3 * Ddim * Ddim;
  u16* Vsuf = Qb;                     // Qb dead after attn3

  wtrans_kernel<<<dim3(32, 32, 4), dim3(256), 0, stream>>>(Wq, Wk, Wv, Wo, WT);
  const float* Xs[3] = {q, k, v};
  const float* bs[3] = {bq, bk, bv};
  for (int z = 0; z < 3; ++z) {
    xcvt_kernel<<<dim3(8192), dim3(256), 0, stream>>>(Xs[z], Xb);
    if (z < 2)
      gemm128_kernel<0><<<dim3(8, 64), dim3(512), 0, stream>>>(
          Xb, WT + (size_t)z * Ddim * Ddim, bs[z], (z == 0) ? Qb : Kb);
    else
      gemm128_kernel<2><<<dim3(8, 64), dim3(512), 0, stream>>>(
          Xb, WT + (size_t)2 * Ddim * Ddim, bs[2], Vt);
  }
  attn3_kernel<<<dim3(8, 64), dim3(256), 0, stream>>>(Qb, Kb, Vt, Ao);
  vscan_kernel<<<dim3(2048), dim3(256), 0, stream>>>(Vt, Vsuf);
  transadd_kernel<<<dim3(32, 2, 64), dim3(256), 0, stream>>>(Vsuf, Ao);
  gemm128_kernel<3><<<dim3(8, 64), dim3(512), 0, stream>>>(Ao, WoT, bo, out);
}